// Round 11
// baseline (430.444 us; speedup 1.0000x reference)
//
#include <hip/hip_runtime.h>
#include <math.h>

typedef __attribute__((ext_vector_type(8))) short short8;
typedef __attribute__((ext_vector_type(4))) float floatx4;

#define TB 16
#define TS 512
#define TD 768
#define TH 12
#define TDH 64
#define TNCH 3

#define SCALE 0.03608439182435161f  // 1/sqrt(768)

__device__ __forceinline__ unsigned short f2bf(float f) {
  unsigned u = __float_as_uint(f);
  u += 0x7fffu + ((u >> 16) & 1u);   // round-to-nearest-even
  return (unsigned short)(u >> 16);
}
__device__ __forceinline__ unsigned f2bf2(float lo, float hi) {
  return (unsigned)f2bf(lo) | ((unsigned)f2bf(hi) << 16);
}

union U4 { uint4 u; short8 s; };

// ===================== prep kernels (one-shot convert/transpose) ============
__global__ __launch_bounds__(256)
void pconv(const float* __restrict__ src, unsigned short* __restrict__ dst) {
  const int i = (blockIdx.x * 256 + threadIdx.x) * 8;
  const float4 a = *(const float4*)&src[i];
  const float4 b = *(const float4*)&src[i + 4];
  uint4 o;
  o.x = f2bf2(a.x, a.y); o.y = f2bf2(a.z, a.w);
  o.z = f2bf2(b.x, b.y); o.w = f2bf2(b.z, b.w);
  *(uint4*)&dst[i] = o;
}

__global__ __launch_bounds__(256)
void ptrans(const float* __restrict__ src, unsigned short* __restrict__ dst,
            int R, int C) {
  __shared__ float ts[32][33];
  const size_t zoff = (size_t)blockIdx.z * R * C;
  src += zoff; dst += zoff;
  const int c0 = blockIdx.x * 32, r0 = blockIdx.y * 32;
  const int x = threadIdx.x & 31, y = threadIdx.x >> 5;   // y in [0,8)
#pragma unroll
  for (int i = 0; i < 4; i++)
    ts[y + 8 * i][x] = src[(size_t)(r0 + y + 8 * i) * C + c0 + x];
  __syncthreads();
#pragma unroll
  for (int i = 0; i < 4; i++)
    dst[(size_t)(c0 + y + 8 * i) * R + r0 + x] = f2bf(ts[x][y + 8 * i]);
}

// ---- GEMM staging: async global->LDS, width 16, linear [128][32] (m97) ----
__device__ __forceinline__ void stage_gll(const unsigned short* __restrict__ S, int ld,
                                          int row0, int k0, int w, int lane,
                                          unsigned short* D) {
  const int rsub = lane >> 2, c = lane & 3;
#pragma unroll
  for (int i = 0; i < 2; i++) {
    const int r = w * 32 + i * 16;
    const unsigned short* g = &S[(size_t)(row0 + r + rsub) * ld + k0 + c * 8];
    unsigned short* d = &D[r * 32];
    __builtin_amdgcn_global_load_lds(
        (const __attribute__((address_space(1))) unsigned int*)(const void*)g,
        (__attribute__((address_space(3))) unsigned int*)(void*)d,
        16, 0, 0);
  }
}

__device__ __forceinline__ void mfma_step_lin(const unsigned short* As, const unsigned short* Bs,
                                              int wy, int wx, int l16, int quad,
                                              floatx4 acc[4][4]) {
  short8 af[4], bfr[4];
#pragma unroll
  for (int i = 0; i < 4; i++) {
    U4 t; t.u = *(const uint4*)&As[(wy * 64 + i * 16 + l16) * 32 + quad * 8];
    af[i] = t.s;
  }
#pragma unroll
  for (int j = 0; j < 4; j++) {
    U4 t; t.u = *(const uint4*)&Bs[(wx * 64 + j * 16 + l16) * 32 + quad * 8];
    bfr[j] = t.s;
  }
#pragma unroll
  for (int i = 0; i < 4; i++)
#pragma unroll
    for (int j = 0; j < 4; j++)
      acc[i][j] = __builtin_amdgcn_mfma_f32_16x16x32_bf16(af[i], bfr[j], acc[i][j], 0, 0, 0);
}

// ===== K1: qk = Htb @ WqkT^T + b_qk -> Q,K (bf16), async-LDS staging =====
__global__ __launch_bounds__(256, 2)
void k1_qk(const unsigned short* __restrict__ Htb, const unsigned short* __restrict__ WqkT,
           const float* __restrict__ bias, unsigned short* __restrict__ Q,
           unsigned short* __restrict__ Ko) {
  __shared__ unsigned short As[128 * 32];
  __shared__ unsigned short Bs[128 * 32];
  const int tid = threadIdx.x;
  const int row0 = blockIdx.y * 128, col0 = blockIdx.x * 128;
  const int w = tid >> 6, lane = tid & 63;
  const int wy = w >> 1, wx = w & 1, l16 = lane & 15, quad = lane >> 4;
  floatx4 acc[4][4];
#pragma unroll
  for (int i = 0; i < 4; i++)
#pragma unroll
    for (int j = 0; j < 4; j++)
#pragma unroll
      for (int r = 0; r < 4; r++) acc[i][j][r] = 0.f;

  for (int k0 = 0; k0 < TD; k0 += 32) {
    stage_gll(Htb, TD, row0, k0, w, lane, As);
    stage_gll(WqkT, TD, col0, k0, w, lane, Bs);
    __syncthreads();
    mfma_step_lin(As, Bs, wy, wx, l16, quad, acc);
    __syncthreads();
  }
#pragma unroll
  for (int i = 0; i < 4; i++)
#pragma unroll
    for (int j = 0; j < 4; j++) {
      const int col = col0 + wx * 64 + j * 16 + l16;
      const float bs = bias[col];
#pragma unroll
      for (int r = 0; r < 4; r++) {
        const int row = row0 + wy * 64 + i * 16 + quad * 4 + r;
        const float v = acc[i][j][r] + bs;
        if (col < TD) Q[(size_t)row * TD + col] = f2bf(v);
        else          Ko[(size_t)row * TD + (col - TD)] = f2bf(v);
      }
    }
}

// ==== K2: MFMA scores; no-max-sub two-pass softmax (R9, verified 128 us) ====
#define OB_S 520
__global__ __launch_bounds__(256, 2)
void k2_attn(const unsigned short* __restrict__ Q, const unsigned short* __restrict__ Kb,
             const float* __restrict__ Ml, const float* __restrict__ am,
             unsigned short* __restrict__ Am) {
  // LDS plan (1040 float4 = 16640 B):
  //   [0, 768)   part[h][q][wave] float4 {Z,d0,d1,d2}   (pass 1)
  //   [768, 960) wlds[h][q] float4 {w0,w1,w2,-}         (pass 2)
  //   epilogue: obuf (16*OB_S ushorts = 16640 B) overlays everything
  __shared__ float4 ldsf4[1040];
  const int i0 = blockIdx.x;
  const int xcd = i0 & 7, jj = i0 >> 3;
  const int b = xcd + 8 * (jj & 1);
  const int q0 = (jj >> 1) * 16;
  const int tid = threadIdx.x;
  const int w = tid >> 6, lane = tid & 63;
  const int l16 = lane & 15, quad = lane >> 4;
  const int kbase = w * 128;

  const float* amb = am + b * TS;
  float amq[4], amk[8], maskv[8];
#pragma unroll
  for (int r = 0; r < 4; r++) amq[r] = amb[q0 + quad * 4 + r];
#pragma unroll
  for (int kt = 0; kt < 8; kt++) {
    amk[kt] = amb[kbase + kt * 16 + l16];
    maskv[kt] = (1.f - amk[kt]) * (-1e9f);
  }

  unsigned Mpk[TNCH][4][4];
#pragma unroll
  for (int i = 0; i < TNCH; i++)
#pragma unroll
    for (int r = 0; r < 4; r++) {
      const float* Mrow = Ml + ((size_t)((b * TNCH + i) * TS + q0 + quad * 4 + r)) * TS;
#pragma unroll
      for (int kt2 = 0; kt2 < 4; kt2++) {
        const int ke = kbase + kt2 * 32 + l16;
        const float me = Mrow[ke] * amk[kt2 * 2] * amq[r];
        const float mo = Mrow[ke + 16] * amk[kt2 * 2 + 1] * amq[r];
        Mpk[i][r][kt2] = f2bf2(me, mo);
      }
    }

  const unsigned short* qbase = Q + ((size_t)(b * TS + q0 + l16)) * TD + quad * 8;
  const unsigned short* kb0   = Kb + ((size_t)(b * TS + kbase + l16)) * TD + quad * 8;

  // ---------------- pass 1: denominators only (barrier-free loop) ----------
  for (int h = 0; h < TH; h++) {
    floatx4 sacc[8];
#pragma unroll
    for (int kt = 0; kt < 8; kt++)
#pragma unroll
      for (int r = 0; r < 4; r++) sacc[kt][r] = 0.f;
#pragma unroll
    for (int dk = 0; dk < 2; dk++) {
      U4 a; a.u = *(const uint4*)(qbase + h * TDH + dk * 32);
#pragma unroll
      for (int kt = 0; kt < 8; kt++) {
        U4 bb; bb.u = *(const uint4*)(kb0 + (size_t)kt * 16 * TD + h * TDH + dk * 32);
        sacc[kt] = __builtin_amdgcn_mfma_f32_16x16x32_bf16(a.s, bb.s, sacc[kt], 0, 0, 0);
      }
    }
    float e[8][4];
    float Zp[4] = {0.f, 0.f, 0.f, 0.f};
#pragma unroll
    for (int kt = 0; kt < 8; kt++)
#pragma unroll
      for (int r = 0; r < 4; r++) {
        const float v = __expf(sacc[kt][r] * SCALE + maskv[kt]);
        e[kt][r] = v;
        Zp[r] += v;
      }
    float dmp[TNCH][4];
#pragma unroll
    for (int i = 0; i < TNCH; i++)
#pragma unroll
      for (int r = 0; r < 4; r++) {
        float d = 0.f;
#pragma unroll
        for (int kt2 = 0; kt2 < 4; kt2++) {
          const unsigned u = Mpk[i][r][kt2];
          d += __uint_as_float(u << 16) * e[kt2 * 2][r];
          d += __uint_as_float(u & 0xffff0000u) * e[kt2 * 2 + 1][r];
        }
        dmp[i][r] = d;
      }
#pragma unroll
    for (int r = 0; r < 4; r++) {
#pragma unroll
      for (int off = 1; off < 16; off <<= 1) {
        Zp[r] += __shfl_xor(Zp[r], off);
        dmp[0][r] += __shfl_xor(dmp[0][r], off);
        dmp[1][r] += __shfl_xor(dmp[1][r], off);
        dmp[2][r] += __shfl_xor(dmp[2][r], off);
      }
    }
    if (l16 == 0) {
#pragma unroll
      for (int r = 0; r < 4; r++)
        ldsf4[(h * 16 + quad * 4 + r) * 4 + w] =
            make_float4(Zp[r], dmp[0][r], dmp[1][r], dmp[2][r]);
    }
  }
  __syncthreads();

  // ---------------- reduce partials -> per-(h,q) channel weights -----------
  if (tid < TH * 16) {
    const int h = tid >> 4, q = tid & 15;
    const int base = (h * 16 + q) * 4;
    const float4 p0 = ldsf4[base + 0];
    const float4 p1 = ldsf4[base + 1];
    const float4 p2 = ldsf4[base + 2];
    const float4 p3 = ldsf4[base + 3];
    const float Z  = p0.x + p1.x + p2.x + p3.x;
    const float d0 = p0.y + p1.y + p2.y + p3.y;
    const float d1 = p0.z + p1.z + p2.z + p3.z;
    const float d2 = p0.w + p1.w + p2.w + p3.w;
    const float ez = 1e-10f * Z + 1e-30f;
    ldsf4[768 + h * 16 + q] =
        make_float4(1.f / (d0 + ez), 1.f / (d1 + ez), 1.f / (d2 + ez), 0.f);
  }
  __syncthreads();

  // ---------------- pass 2: recompute e, accumulate (barrier-free loop) ----
  float acc[TNCH][8][4];
#pragma unroll
  for (int i = 0; i < TNCH; i++)
#pragma unroll
    for (int kt = 0; kt < 8; kt++)
#pragma unroll
      for (int r = 0; r < 4; r++) acc[i][kt][r] = 0.f;

  for (int h = 0; h < TH; h++) {
    floatx4 sacc[8];
#pragma unroll
    for (int kt = 0; kt < 8; kt++)
#pragma unroll
      for (int r = 0; r < 4; r++) sacc[kt][r] = 0.f;
#pragma unroll
    for (int dk = 0; dk < 2; dk++) {
      U4 a; a.u = *(const uint4*)(qbase + h * TDH + dk * 32);
#pragma unroll
      for (int kt = 0; kt < 8; kt++) {
        U4 bb; bb.u = *(const uint4*)(kb0 + (size_t)kt * 16 * TD + h * TDH + dk * 32);
        sacc[kt] = __builtin_amdgcn_mfma_f32_16x16x32_bf16(a.s, bb.s, sacc[kt], 0, 0, 0);
      }
    }
    float4 wv[4];
#pragma unroll
    for (int r = 0; r < 4; r++) wv[r] = ldsf4[768 + h * 16 + quad * 4 + r];
#pragma unroll
    for (int kt = 0; kt < 8; kt++)
#pragma unroll
      for (int r = 0; r < 4; r++) {
        const float v = __expf(sacc[kt][r] * SCALE + maskv[kt]);
        acc[0][kt][r] += v * wv[r].x;
        acc[1][kt][r] += v * wv[r].y;
        acc[2][kt][r] += v * wv[r].z;
      }
  }
  __syncthreads();   // protect obuf overlay of part/wlds

  // ---------------- epilogue: Am = bf16(M * acc / 12), staged via LDS ------
  unsigned short* obuf = (unsigned short*)ldsf4;
  const float inv_h = 1.f / (float)TH;
  for (int i = 0; i < TNCH; i++) {
#pragma unroll
    for (int r = 0; r < 4; r++) {
      const int q = q0 + quad * 4 + r;
      const float* Mrow = Ml + ((size_t)((b * TNCH + i) * TS + q)) * TS;
#pragma unroll
      for (int kt = 0; kt < 8; kt++) {
        const int k = kbase + kt * 16 + l16;
        const float mv = Mrow[k] * amk[kt] * amq[r];
        obuf[(quad * 4 + r) * OB_S + k] = f2bf(mv * acc[i][kt][r] * inv_h);
      }
    }
    __syncthreads();
#pragma unroll
    for (int it = 0; it < 4; it++) {
      const int idx = tid + it * 256;
      const int row = idx >> 6, c16 = idx & 63;
      const uint4 v = *(const uint4*)&obuf[row * OB_S + c16 * 8];
      *(uint4*)&Am[((size_t)((i * TB + b) * TS + q0 + row)) * TS + c16 * 8] = v;
    }
    __syncthreads();
  }
}

// ===== K3: G[z] = Am[z] @ HtbT[b]^T -> bf16, async-LDS staging =====
__global__ __launch_bounds__(256, 2)
void k3_feat(const unsigned short* __restrict__ Am, const unsigned short* __restrict__ HtbT,
             unsigned short* __restrict__ G) {
  __shared__ unsigned short As[128 * 32];
  __shared__ unsigned short Bs[128 * 32];
  const int z = blockIdx.z;
  const int b = z & 15;
  const unsigned short* A  = Am + (size_t)z * TS * TS;
  const unsigned short* Bt = HtbT + (size_t)b * TD * TS;
  unsigned short* C = G + (size_t)z * TS * TD;
  const int tid = threadIdx.x;
  const int row0 = blockIdx.y * 128, col0 = blockIdx.x * 128;
  const int w = tid >> 6, lane = tid & 63;
  const int wy = w >> 1, wx = w & 1, l16 = lane & 15, quad = lane >> 4;
  floatx4 acc[4][4];
#pragma unroll
  for (int i = 0; i < 4; i++)
#pragma unroll
    for (int j = 0; j < 4; j++)
#pragma unroll
      for (int r = 0; r < 4; r++) acc[i][j][r] = 0.f;

  for (int k0 = 0; k0 < TS; k0 += 32) {
    stage_gll(A, TS, row0, k0, w, lane, As);
    stage_gll(Bt, TS, col0, k0, w, lane, Bs);
    __syncthreads();
    mfma_step_lin(As, Bs, wy, wx, l16, quad, acc);
    __syncthreads();
  }
#pragma unroll
  for (int i = 0; i < 4; i++)
#pragma unroll
    for (int j = 0; j < 4; j++) {
      const int col = col0 + wx * 64 + j * 16 + l16;
#pragma unroll
      for (int r = 0; r < 4; r++) {
        const int row = row0 + wy * 64 + i * 16 + quad * 4 + r;
        C[(size_t)row * TD + col] = f2bf(acc[i][j][r]);
      }
    }
}

// == K4 (R15): wide-N tile 64x384, grid (2,128)=256 blocks = 1/CU balanced ==
// A (G rows) fetched once per col-half (2x total, was 8x); W stays in L2.
// Per-output k-order identical to before -> bitwise-identical output.
__global__ __launch_bounds__(256, 1)
void k4_out(const unsigned short* __restrict__ G, const unsigned short* __restrict__ WgT,
            const float* __restrict__ bg, const float* __restrict__ am,
            float* __restrict__ out) {
  __shared__ unsigned short As[64 * 32];    // 4 KB
  __shared__ unsigned short Bs[384 * 32];   // 24 KB
  const int tid = threadIdx.x;
  const int w = tid >> 6, lane = tid & 63;
  const int l16 = lane & 15, quad = lane >> 4;
  const int rsub = lane >> 2, cch = lane & 3;
  const int row0 = blockIdx.y * 64;         // 0..8128 over 16*512 rows
  const int col0 = blockIdx.x * 384;        // 0 or 384

  float osum[24][4];
#pragma unroll
  for (int j = 0; j < 24; j++)
#pragma unroll
    for (int r = 0; r < 4; r++) osum[j][r] = 0.f;

  for (int ch = 0; ch < TNCH; ch++) {
    const unsigned short* A  = G + (size_t)ch * (TB * TS) * TD;
    const unsigned short* Bt = WgT + (size_t)ch * TD * TD;
    floatx4 acc[24];
#pragma unroll
    for (int j = 0; j < 24; j++)
#pragma unroll
      for (int r = 0; r < 4; r++) acc[j][r] = 0.f;

    for (int k0 = 0; k0 < TD; k0 += 32) {
      // A: 64 rows x 32 k — one issue per wave (wave w covers rows w*16..+15)
      {
        const unsigned short* g = &A[(size_t)(row0 + w * 16 + rsub) * TD + k0 + cch * 8];
        __builtin_amdgcn_global_load_lds(
            (const __attribute__((address_space(1))) unsigned int*)(const void*)g,
            (__attribute__((address_space(3))) unsigned int*)(void*)&As[(w * 16) * 32],
            16, 0, 0);
      }
      // B: 384 rows x 32 k — 6 issues per wave
#pragma unroll
      for (int i = 0; i < 6; i++) {
        const int r = i * 64 + w * 16;
        const unsigned short* g = &Bt[(size_t)(col0 + r + rsub) * TD + k0 + cch * 8];
        __builtin_amdgcn_global_load_lds(
            (const __attribute__((address_space(1))) unsigned int*)(const void*)g,
            (__attribute__((address_space(3))) unsigned int*)(void*)&Bs[r * 32],
            16, 0, 0);
      }
      __syncthreads();
      U4 a; a.u = *(const uint4*)&As[(w * 16 + l16) * 32 + quad * 8];
#pragma unroll
      for (int j = 0; j < 24; j++) {
        U4 bb; bb.u = *(const uint4*)&Bs[(j * 16 + l16) * 32 + quad * 8];
        acc[j] = __builtin_amdgcn_mfma_f32_16x16x32_bf16(a.s, bb.s, acc[j], 0, 0, 0);
      }
      __syncthreads();
    }
#pragma unroll
    for (int j = 0; j < 24; j++) {
      const float bs = bg[ch * TD + col0 + j * 16 + l16];
#pragma unroll
      for (int r = 0; r < 4; r++)
        osum[j][r] += fmaxf(acc[j][r] + bs, 0.f);
    }
  }
#pragma unroll
  for (int r = 0; r < 4; r++) {
    const int row = row0 + w * 16 + quad * 4 + r;
    const float amr = am[row] * (1.f / 3.f);
#pragma unroll
    for (int j = 0; j < 24; j++) {
      const int col = col0 + j * 16 + l16;
      out[(size_t)row * TD + col] = osum[j][r] * amr;
    }
  }
}

extern "C" void kernel_launch(void* const* d_in, const int* in_sizes, int n_in,
                              void* d_out, int out_size, void* d_ws, size_t ws_size,
                              hipStream_t stream) {
  const float* Ht    = (const float*)d_in[0];
  const float* Ml    = (const float*)d_in[1];
  const float* am    = (const float*)d_in[2];
  const float* W_qk  = (const float*)d_in[3];
  const float* b_qk  = (const float*)d_in[4];
  const float* W_gat = (const float*)d_in[5];
  const float* b_gat = (const float*)d_in[6];
  float* out = (float*)d_out;

  // ws layout (ushorts):
  //   Q     [0,          6291456)
  //   K     [6291456,   12582912)
  //   Htb   [12582912,  18874368)   bf16(Ht), A-operand for k1
  //   HtbT  [18874368,  25165824)   per-b [768][512], B-operand for k3
  //   WqkT  [25165824,  26345472)   [1536][768]
  //   WgT   [26345472,  28114944)   [3][768][768]
  //   Am    [28114944,  40697856)
  //   G     [0,         18874368)   overlays Q/K/Htb (dead after k2/k1)
  unsigned short* base = (unsigned short*)d_ws;
  const size_t SEG = (size_t)TB * TS * TD;            // 6291456
  unsigned short* Q    = base;
  unsigned short* Kw   = base + SEG;
  unsigned short* Htb  = base + 2 * SEG;
  unsigned short* HtbT = base + 3 * SEG;
  unsigned short* WqkT = base + 4 * SEG;
  unsigned short* WgT  = WqkT + (size_t)TD * 2 * TD;
  unsigned short* Am   = WgT + (size_t)TNCH * TD * TD;
  unsigned short* G    = base;

  // prep: bf16 conversions + transposes (one-shot, ~100 MB traffic)
  pconv <<<dim3(3072), 256, 0, stream>>>(Ht, Htb);
  ptrans<<<dim3(24, 16, 16), 256, 0, stream>>>(Ht, HtbT, TS, TD);
  ptrans<<<dim3(48, 24, 1),  256, 0, stream>>>(W_qk, WqkT, TD, 2 * TD);
  ptrans<<<dim3(24, 24, 3),  256, 0, stream>>>(W_gat, WgT, TD, TD);

  k1_qk  <<<dim3(12, 64), 256, 0, stream>>>(Htb, WqkT, b_qk, Q, Kw);
  k2_attn<<<dim3(512), 256, 0, stream>>>(Q, Kw, Ml, am, Am);
  k3_feat<<<dim3(6, 4, 48), 256, 0, stream>>>(Am, HtbT, G);
  k4_out <<<dim3(2, 128), 256, 0, stream>>>(G, WgT, b_gat, am, out);
}

// Round 12
// 424.991 us; speedup vs baseline: 1.0128x; 1.0128x over previous
//
#include <hip/hip_runtime.h>
#include <math.h>

typedef __attribute__((ext_vector_type(8))) short short8;
typedef __attribute__((ext_vector_type(4))) float floatx4;

#define TB 16
#define TS 512
#define TD 768
#define TH 12
#define TDH 64
#define TNCH 3

#define SCALE 0.03608439182435161f  // 1/sqrt(768)

__device__ __forceinline__ unsigned short f2bf(float f) {
  unsigned u = __float_as_uint(f);
  u += 0x7fffu + ((u >> 16) & 1u);   // round-to-nearest-even
  return (unsigned short)(u >> 16);
}
__device__ __forceinline__ unsigned f2bf2(float lo, float hi) {
  return (unsigned)f2bf(lo) | ((unsigned)f2bf(hi) << 16);
}

union U4 { uint4 u; short8 s; };

// ===================== prep kernels (one-shot convert/transpose) ============
__global__ __launch_bounds__(256)
void pconv(const float* __restrict__ src, unsigned short* __restrict__ dst) {
  const int i = (blockIdx.x * 256 + threadIdx.x) * 8;
  const float4 a = *(const float4*)&src[i];
  const float4 b = *(const float4*)&src[i + 4];
  uint4 o;
  o.x = f2bf2(a.x, a.y); o.y = f2bf2(a.z, a.w);
  o.z = f2bf2(b.x, b.y); o.w = f2bf2(b.z, b.w);
  *(uint4*)&dst[i] = o;
}

__global__ __launch_bounds__(256)
void ptrans(const float* __restrict__ src, unsigned short* __restrict__ dst,
            int R, int C) {
  __shared__ float ts[32][33];
  const size_t zoff = (size_t)blockIdx.z * R * C;
  src += zoff; dst += zoff;
  const int c0 = blockIdx.x * 32, r0 = blockIdx.y * 32;
  const int x = threadIdx.x & 31, y = threadIdx.x >> 5;   // y in [0,8)
#pragma unroll
  for (int i = 0; i < 4; i++)
    ts[y + 8 * i][x] = src[(size_t)(r0 + y + 8 * i) * C + c0 + x];
  __syncthreads();
#pragma unroll
  for (int i = 0; i < 4; i++)
    dst[(size_t)(c0 + y + 8 * i) * R + r0 + x] = f2bf(ts[x][y + 8 * i]);
}

// ---- GEMM staging: async global->LDS, width 16, linear [128][32] (m97) ----
__device__ __forceinline__ void stage_gll(const unsigned short* __restrict__ S, int ld,
                                          int row0, int k0, int w, int lane,
                                          unsigned short* D) {
  const int rsub = lane >> 2, c = lane & 3;
#pragma unroll
  for (int i = 0; i < 2; i++) {
    const int r = w * 32 + i * 16;
    const unsigned short* g = &S[(size_t)(row0 + r + rsub) * ld + k0 + c * 8];
    unsigned short* d = &D[r * 32];
    __builtin_amdgcn_global_load_lds(
        (const __attribute__((address_space(1))) unsigned int*)(const void*)g,
        (__attribute__((address_space(3))) unsigned int*)(void*)d,
        16, 0, 0);
  }
}

__device__ __forceinline__ void mfma_step_lin(const unsigned short* As, const unsigned short* Bs,
                                              int wy, int wx, int l16, int quad,
                                              floatx4 acc[4][4]) {
  short8 af[4], bfr[4];
#pragma unroll
  for (int i = 0; i < 4; i++) {
    U4 t; t.u = *(const uint4*)&As[(wy * 64 + i * 16 + l16) * 32 + quad * 8];
    af[i] = t.s;
  }
#pragma unroll
  for (int j = 0; j < 4; j++) {
    U4 t; t.u = *(const uint4*)&Bs[(wx * 64 + j * 16 + l16) * 32 + quad * 8];
    bfr[j] = t.s;
  }
#pragma unroll
  for (int i = 0; i < 4; i++)
#pragma unroll
    for (int j = 0; j < 4; j++)
      acc[i][j] = __builtin_amdgcn_mfma_f32_16x16x32_bf16(af[i], bfr[j], acc[i][j], 0, 0, 0);
}

// ===== K1: qk = Htb @ WqkT^T + b_qk -> Q,K (bf16), async-LDS staging =====
__global__ __launch_bounds__(256, 2)
void k1_qk(const unsigned short* __restrict__ Htb, const unsigned short* __restrict__ WqkT,
           const float* __restrict__ bias, unsigned short* __restrict__ Q,
           unsigned short* __restrict__ Ko) {
  __shared__ unsigned short As[128 * 32];
  __shared__ unsigned short Bs[128 * 32];
  const int tid = threadIdx.x;
  const int row0 = blockIdx.y * 128, col0 = blockIdx.x * 128;
  const int w = tid >> 6, lane = tid & 63;
  const int wy = w >> 1, wx = w & 1, l16 = lane & 15, quad = lane >> 4;
  floatx4 acc[4][4];
#pragma unroll
  for (int i = 0; i < 4; i++)
#pragma unroll
    for (int j = 0; j < 4; j++)
#pragma unroll
      for (int r = 0; r < 4; r++) acc[i][j][r] = 0.f;

  for (int k0 = 0; k0 < TD; k0 += 32) {
    stage_gll(Htb, TD, row0, k0, w, lane, As);
    stage_gll(WqkT, TD, col0, k0, w, lane, Bs);
    __syncthreads();
    mfma_step_lin(As, Bs, wy, wx, l16, quad, acc);
    __syncthreads();
  }
#pragma unroll
  for (int i = 0; i < 4; i++)
#pragma unroll
    for (int j = 0; j < 4; j++) {
      const int col = col0 + wx * 64 + j * 16 + l16;
      const float bs = bias[col];
#pragma unroll
      for (int r = 0; r < 4; r++) {
        const int row = row0 + wy * 64 + i * 16 + quad * 4 + r;
        const float v = acc[i][j][r] + bs;
        if (col < TD) Q[(size_t)row * TD + col] = f2bf(v);
        else          Ko[(size_t)row * TD + (col - TD)] = f2bf(v);
      }
    }
}

// ==== K2: MFMA scores; no-max-sub two-pass softmax (R9, verified 128 us) ====
#define OB_S 520
__global__ __launch_bounds__(256, 2)
void k2_attn(const unsigned short* __restrict__ Q, const unsigned short* __restrict__ Kb,
             const float* __restrict__ Ml, const float* __restrict__ am,
             unsigned short* __restrict__ Am) {
  // LDS plan (1040 float4 = 16640 B):
  //   [0, 768)   part[h][q][wave] float4 {Z,d0,d1,d2}   (pass 1)
  //   [768, 960) wlds[h][q] float4 {w0,w1,w2,-}         (pass 2)
  //   epilogue: obuf (16*OB_S ushorts = 16640 B) overlays everything
  __shared__ float4 ldsf4[1040];
  const int i0 = blockIdx.x;
  const int xcd = i0 & 7, jj = i0 >> 3;
  const int b = xcd + 8 * (jj & 1);
  const int q0 = (jj >> 1) * 16;
  const int tid = threadIdx.x;
  const int w = tid >> 6, lane = tid & 63;
  const int l16 = lane & 15, quad = lane >> 4;
  const int kbase = w * 128;

  const float* amb = am + b * TS;
  float amq[4], amk[8], maskv[8];
#pragma unroll
  for (int r = 0; r < 4; r++) amq[r] = amb[q0 + quad * 4 + r];
#pragma unroll
  for (int kt = 0; kt < 8; kt++) {
    amk[kt] = amb[kbase + kt * 16 + l16];
    maskv[kt] = (1.f - amk[kt]) * (-1e9f);
  }

  unsigned Mpk[TNCH][4][4];
#pragma unroll
  for (int i = 0; i < TNCH; i++)
#pragma unroll
    for (int r = 0; r < 4; r++) {
      const float* Mrow = Ml + ((size_t)((b * TNCH + i) * TS + q0 + quad * 4 + r)) * TS;
#pragma unroll
      for (int kt2 = 0; kt2 < 4; kt2++) {
        const int ke = kbase + kt2 * 32 + l16;
        const float me = Mrow[ke] * amk[kt2 * 2] * amq[r];
        const float mo = Mrow[ke + 16] * amk[kt2 * 2 + 1] * amq[r];
        Mpk[i][r][kt2] = f2bf2(me, mo);
      }
    }

  const unsigned short* qbase = Q + ((size_t)(b * TS + q0 + l16)) * TD + quad * 8;
  const unsigned short* kb0   = Kb + ((size_t)(b * TS + kbase + l16)) * TD + quad * 8;

  // ---------------- pass 1: denominators only (barrier-free loop) ----------
  for (int h = 0; h < TH; h++) {
    floatx4 sacc[8];
#pragma unroll
    for (int kt = 0; kt < 8; kt++)
#pragma unroll
      for (int r = 0; r < 4; r++) sacc[kt][r] = 0.f;
#pragma unroll
    for (int dk = 0; dk < 2; dk++) {
      U4 a; a.u = *(const uint4*)(qbase + h * TDH + dk * 32);
#pragma unroll
      for (int kt = 0; kt < 8; kt++) {
        U4 bb; bb.u = *(const uint4*)(kb0 + (size_t)kt * 16 * TD + h * TDH + dk * 32);
        sacc[kt] = __builtin_amdgcn_mfma_f32_16x16x32_bf16(a.s, bb.s, sacc[kt], 0, 0, 0);
      }
    }
    float e[8][4];
    float Zp[4] = {0.f, 0.f, 0.f, 0.f};
#pragma unroll
    for (int kt = 0; kt < 8; kt++)
#pragma unroll
      for (int r = 0; r < 4; r++) {
        const float v = __expf(sacc[kt][r] * SCALE + maskv[kt]);
        e[kt][r] = v;
        Zp[r] += v;
      }
    float dmp[TNCH][4];
#pragma unroll
    for (int i = 0; i < TNCH; i++)
#pragma unroll
      for (int r = 0; r < 4; r++) {
        float d = 0.f;
#pragma unroll
        for (int kt2 = 0; kt2 < 4; kt2++) {
          const unsigned u = Mpk[i][r][kt2];
          d += __uint_as_float(u << 16) * e[kt2 * 2][r];
          d += __uint_as_float(u & 0xffff0000u) * e[kt2 * 2 + 1][r];
        }
        dmp[i][r] = d;
      }
#pragma unroll
    for (int r = 0; r < 4; r++) {
#pragma unroll
      for (int off = 1; off < 16; off <<= 1) {
        Zp[r] += __shfl_xor(Zp[r], off);
        dmp[0][r] += __shfl_xor(dmp[0][r], off);
        dmp[1][r] += __shfl_xor(dmp[1][r], off);
        dmp[2][r] += __shfl_xor(dmp[2][r], off);
      }
    }
    if (l16 == 0) {
#pragma unroll
      for (int r = 0; r < 4; r++)
        ldsf4[(h * 16 + quad * 4 + r) * 4 + w] =
            make_float4(Zp[r], dmp[0][r], dmp[1][r], dmp[2][r]);
    }
  }
  __syncthreads();

  // ---------------- reduce partials -> per-(h,q) channel weights -----------
  if (tid < TH * 16) {
    const int h = tid >> 4, q = tid & 15;
    const int base = (h * 16 + q) * 4;
    const float4 p0 = ldsf4[base + 0];
    const float4 p1 = ldsf4[base + 1];
    const float4 p2 = ldsf4[base + 2];
    const float4 p3 = ldsf4[base + 3];
    const float Z  = p0.x + p1.x + p2.x + p3.x;
    const float d0 = p0.y + p1.y + p2.y + p3.y;
    const float d1 = p0.z + p1.z + p2.z + p3.z;
    const float d2 = p0.w + p1.w + p2.w + p3.w;
    const float ez = 1e-10f * Z + 1e-30f;
    ldsf4[768 + h * 16 + q] =
        make_float4(1.f / (d0 + ez), 1.f / (d1 + ez), 1.f / (d2 + ez), 0.f);
  }
  __syncthreads();

  // ---------------- pass 2: recompute e, accumulate (barrier-free loop) ----
  float acc[TNCH][8][4];
#pragma unroll
  for (int i = 0; i < TNCH; i++)
#pragma unroll
    for (int kt = 0; kt < 8; kt++)
#pragma unroll
      for (int r = 0; r < 4; r++) acc[i][kt][r] = 0.f;

  for (int h = 0; h < TH; h++) {
    floatx4 sacc[8];
#pragma unroll
    for (int kt = 0; kt < 8; kt++)
#pragma unroll
      for (int r = 0; r < 4; r++) sacc[kt][r] = 0.f;
#pragma unroll
    for (int dk = 0; dk < 2; dk++) {
      U4 a; a.u = *(const uint4*)(qbase + h * TDH + dk * 32);
#pragma unroll
      for (int kt = 0; kt < 8; kt++) {
        U4 bb; bb.u = *(const uint4*)(kb0 + (size_t)kt * 16 * TD + h * TDH + dk * 32);
        sacc[kt] = __builtin_amdgcn_mfma_f32_16x16x32_bf16(a.s, bb.s, sacc[kt], 0, 0, 0);
      }
    }
    float4 wv[4];
#pragma unroll
    for (int r = 0; r < 4; r++) wv[r] = ldsf4[768 + h * 16 + quad * 4 + r];
#pragma unroll
    for (int kt = 0; kt < 8; kt++)
#pragma unroll
      for (int r = 0; r < 4; r++) {
        const float v = __expf(sacc[kt][r] * SCALE + maskv[kt]);
        acc[0][kt][r] += v * wv[r].x;
        acc[1][kt][r] += v * wv[r].y;
        acc[2][kt][r] += v * wv[r].z;
      }
  }
  __syncthreads();   // protect obuf overlay of part/wlds

  // ---------------- epilogue: Am = bf16(M * acc / 12), staged via LDS ------
  unsigned short* obuf = (unsigned short*)ldsf4;
  const float inv_h = 1.f / (float)TH;
  for (int i = 0; i < TNCH; i++) {
#pragma unroll
    for (int r = 0; r < 4; r++) {
      const int q = q0 + quad * 4 + r;
      const float* Mrow = Ml + ((size_t)((b * TNCH + i) * TS + q)) * TS;
#pragma unroll
      for (int kt = 0; kt < 8; kt++) {
        const int k = kbase + kt * 16 + l16;
        const float mv = Mrow[k] * amk[kt] * amq[r];
        obuf[(quad * 4 + r) * OB_S + k] = f2bf(mv * acc[i][kt][r] * inv_h);
      }
    }
    __syncthreads();
#pragma unroll
    for (int it = 0; it < 4; it++) {
      const int idx = tid + it * 256;
      const int row = idx >> 6, c16 = idx & 63;
      const uint4 v = *(const uint4*)&obuf[row * OB_S + c16 * 8];
      *(uint4*)&Am[((size_t)((i * TB + b) * TS + q0 + row)) * TS + c16 * 8] = v;
    }
    __syncthreads();
  }
}

// ===== K3: G[z] = Am[z] @ HtbT[b]^T -> bf16, async-LDS staging =====
__global__ __launch_bounds__(256, 2)
void k3_feat(const unsigned short* __restrict__ Am, const unsigned short* __restrict__ HtbT,
             unsigned short* __restrict__ G) {
  __shared__ unsigned short As[128 * 32];
  __shared__ unsigned short Bs[128 * 32];
  const int z = blockIdx.z;
  const int b = z & 15;
  const unsigned short* A  = Am + (size_t)z * TS * TS;
  const unsigned short* Bt = HtbT + (size_t)b * TD * TS;
  unsigned short* C = G + (size_t)z * TS * TD;
  const int tid = threadIdx.x;
  const int row0 = blockIdx.y * 128, col0 = blockIdx.x * 128;
  const int w = tid >> 6, lane = tid & 63;
  const int wy = w >> 1, wx = w & 1, l16 = lane & 15, quad = lane >> 4;
  floatx4 acc[4][4];
#pragma unroll
  for (int i = 0; i < 4; i++)
#pragma unroll
    for (int j = 0; j < 4; j++)
#pragma unroll
      for (int r = 0; r < 4; r++) acc[i][j][r] = 0.f;

  for (int k0 = 0; k0 < TS; k0 += 32) {
    stage_gll(A, TS, row0, k0, w, lane, As);
    stage_gll(Bt, TS, col0, k0, w, lane, Bs);
    __syncthreads();
    mfma_step_lin(As, Bs, wy, wx, l16, quad, acc);
    __syncthreads();
  }
#pragma unroll
  for (int i = 0; i < 4; i++)
#pragma unroll
    for (int j = 0; j < 4; j++) {
      const int col = col0 + wx * 64 + j * 16 + l16;
#pragma unroll
      for (int r = 0; r < 4; r++) {
        const int row = row0 + wy * 64 + i * 16 + quad * 4 + r;
        C[(size_t)row * TD + col] = f2bf(acc[i][j][r]);
      }
    }
}

// == K4 (R16): channel-split GEMM, grid (6,64,3)=1152 blocks = 4.5/CU.      ==
// Each block: one channel's 128x128 tile; out += relu(acc+bg)*am/3 via
// fp32 atomicAdd (3-way contention only). out zeroed in-graph by memset.
__global__ __launch_bounds__(256, 4)
void k4_out(const unsigned short* __restrict__ G, const unsigned short* __restrict__ WgT,
            const float* __restrict__ bg, const float* __restrict__ am,
            float* __restrict__ out) {
  __shared__ unsigned short As[128 * 32];
  __shared__ unsigned short Bs[128 * 32];
  const int tid = threadIdx.x;
  const int ch = blockIdx.z;
  const int row0 = blockIdx.y * 128, col0 = blockIdx.x * 128;
  const int w = tid >> 6, lane = tid & 63;
  const int wy = w >> 1, wx = w & 1, l16 = lane & 15, quad = lane >> 4;
  const unsigned short* A  = G + (size_t)ch * (TB * TS) * TD;
  const unsigned short* Bt = WgT + (size_t)ch * TD * TD;

  floatx4 acc[4][4];
#pragma unroll
  for (int i = 0; i < 4; i++)
#pragma unroll
    for (int j = 0; j < 4; j++)
#pragma unroll
      for (int r = 0; r < 4; r++) acc[i][j][r] = 0.f;

  for (int k0 = 0; k0 < TD; k0 += 32) {
    stage_gll(A, TD, row0, k0, w, lane, As);
    stage_gll(Bt, TD, col0, k0, w, lane, Bs);
    __syncthreads();
    mfma_step_lin(As, Bs, wy, wx, l16, quad, acc);
    __syncthreads();
  }
#pragma unroll
  for (int i = 0; i < 4; i++)
#pragma unroll
    for (int j = 0; j < 4; j++) {
      const int col = col0 + wx * 64 + j * 16 + l16;
      const float bs = bg[ch * TD + col];
#pragma unroll
      for (int r = 0; r < 4; r++) {
        const int row = row0 + wy * 64 + i * 16 + quad * 4 + r;
        const float v = fmaxf(acc[i][j][r] + bs, 0.f) * am[row] * (1.f / 3.f);
        atomicAdd(&out[(size_t)row * TD + col], v);
      }
    }
}

extern "C" void kernel_launch(void* const* d_in, const int* in_sizes, int n_in,
                              void* d_out, int out_size, void* d_ws, size_t ws_size,
                              hipStream_t stream) {
  const float* Ht    = (const float*)d_in[0];
  const float* Ml    = (const float*)d_in[1];
  const float* am    = (const float*)d_in[2];
  const float* W_qk  = (const float*)d_in[3];
  const float* b_qk  = (const float*)d_in[4];
  const float* W_gat = (const float*)d_in[5];
  const float* b_gat = (const float*)d_in[6];
  float* out = (float*)d_out;

  // ws layout (ushorts):
  //   Q     [0,          6291456)
  //   K     [6291456,   12582912)
  //   Htb   [12582912,  18874368)   bf16(Ht), A-operand for k1
  //   HtbT  [18874368,  25165824)   per-b [768][512], B-operand for k3
  //   WqkT  [25165824,  26345472)   [1536][768]
  //   WgT   [26345472,  28114944)   [3][768][768]
  //   Am    [28114944,  40697856)
  //   G     [0,         18874368)   overlays Q/K/Htb (dead after k2/k1)
  unsigned short* base = (unsigned short*)d_ws;
  const size_t SEG = (size_t)TB * TS * TD;            // 6291456
  unsigned short* Q    = base;
  unsigned short* Kw   = base + SEG;
  unsigned short* Htb  = base + 2 * SEG;
  unsigned short* HtbT = base + 3 * SEG;
  unsigned short* WqkT = base + 4 * SEG;
  unsigned short* WgT  = WqkT + (size_t)TD * 2 * TD;
  unsigned short* Am   = WgT + (size_t)TNCH * TD * TD;
  unsigned short* G    = base;

  // out must start at zero every launch (k4 accumulates atomically)
  hipMemsetAsync(out, 0, (size_t)TB * TS * TD * sizeof(float), stream);

  // prep: bf16 conversions + transposes (one-shot, ~100 MB traffic)
  pconv <<<dim3(3072), 256, 0, stream>>>(Ht, Htb);
  ptrans<<<dim3(24, 16, 16), 256, 0, stream>>>(Ht, HtbT, TS, TD);
  ptrans<<<dim3(48, 24, 1),  256, 0, stream>>>(W_qk, WqkT, TD, 2 * TD);
  ptrans<<<dim3(24, 24, 3),  256, 0, stream>>>(W_gat, WgT, TD, TD);

  k1_qk  <<<dim3(12, 64), 256, 0, stream>>>(Htb, WqkT, b_qk, Q, Kw);
  k2_attn<<<dim3(512), 256, 0, stream>>>(Q, Kw, Ml, am, Am);
  k3_feat<<<dim3(6, 4, 48), 256, 0, stream>>>(Am, HtbT, G);
  k4_out <<<dim3(6, 64, 3), 256, 0, stream>>>(G, WgT, b_gat, am, out);
}

// Round 13
// 382.184 us; speedup vs baseline: 1.1263x; 1.1120x over previous
//
#include <hip/hip_runtime.h>
#include <math.h>

typedef __attribute__((ext_vector_type(8))) short short8;
typedef __attribute__((ext_vector_type(4))) float floatx4;

#define TB 16
#define TS 512
#define TD 768
#define TH 12
#define TDH 64
#define TNCH 3

#define SCALE 0.03608439182435161f  // 1/sqrt(768)

__device__ __forceinline__ unsigned short f2bf(float f) {
  unsigned u = __float_as_uint(f);
  u += 0x7fffu + ((u >> 16) & 1u);   // round-to-nearest-even
  return (unsigned short)(u >> 16);
}
__device__ __forceinline__ unsigned f2bf2(float lo, float hi) {
  return (unsigned)f2bf(lo) | ((unsigned)f2bf(hi) << 16);
}

union U4 { uint4 u; short8 s; };

// ===================== prep kernels (one-shot convert/transpose) ============
__global__ __launch_bounds__(256)
void pconv(const float* __restrict__ src, unsigned short* __restrict__ dst) {
  const int i = (blockIdx.x * 256 + threadIdx.x) * 8;
  const float4 a = *(const float4*)&src[i];
  const float4 b = *(const float4*)&src[i + 4];
  uint4 o;
  o.x = f2bf2(a.x, a.y); o.y = f2bf2(a.z, a.w);
  o.z = f2bf2(b.x, b.y); o.w = f2bf2(b.z, b.w);
  *(uint4*)&dst[i] = o;
}

__global__ __launch_bounds__(256)
void ptrans(const float* __restrict__ src, unsigned short* __restrict__ dst,
            int R, int C) {
  __shared__ float ts[32][33];
  const size_t zoff = (size_t)blockIdx.z * R * C;
  src += zoff; dst += zoff;
  const int c0 = blockIdx.x * 32, r0 = blockIdx.y * 32;
  const int x = threadIdx.x & 31, y = threadIdx.x >> 5;   // y in [0,8)
#pragma unroll
  for (int i = 0; i < 4; i++)
    ts[y + 8 * i][x] = src[(size_t)(r0 + y + 8 * i) * C + c0 + x];
  __syncthreads();
#pragma unroll
  for (int i = 0; i < 4; i++)
    dst[(size_t)(c0 + y + 8 * i) * R + r0 + x] = f2bf(ts[x][y + 8 * i]);
}

// ---- GEMM staging: async global->LDS, width 16, linear [128][32] (m97) ----
__device__ __forceinline__ void stage_gll(const unsigned short* __restrict__ S, int ld,
                                          int row0, int k0, int w, int lane,
                                          unsigned short* D) {
  const int rsub = lane >> 2, c = lane & 3;
#pragma unroll
  for (int i = 0; i < 2; i++) {
    const int r = w * 32 + i * 16;
    const unsigned short* g = &S[(size_t)(row0 + r + rsub) * ld + k0 + c * 8];
    unsigned short* d = &D[r * 32];
    __builtin_amdgcn_global_load_lds(
        (const __attribute__((address_space(1))) unsigned int*)(const void*)g,
        (__attribute__((address_space(3))) unsigned int*)(void*)d,
        16, 0, 0);
  }
}

__device__ __forceinline__ void mfma_step_lin(const unsigned short* As, const unsigned short* Bs,
                                              int wy, int wx, int l16, int quad,
                                              floatx4 acc[4][4]) {
  short8 af[4], bfr[4];
#pragma unroll
  for (int i = 0; i < 4; i++) {
    U4 t; t.u = *(const uint4*)&As[(wy * 64 + i * 16 + l16) * 32 + quad * 8];
    af[i] = t.s;
  }
#pragma unroll
  for (int j = 0; j < 4; j++) {
    U4 t; t.u = *(const uint4*)&Bs[(wx * 64 + j * 16 + l16) * 32 + quad * 8];
    bfr[j] = t.s;
  }
#pragma unroll
  for (int i = 0; i < 4; i++)
#pragma unroll
    for (int j = 0; j < 4; j++)
      acc[i][j] = __builtin_amdgcn_mfma_f32_16x16x32_bf16(af[i], bfr[j], acc[i][j], 0, 0, 0);
}

// ===== K1: qk = Htb @ WqkT^T + b_qk -> Q,K (bf16), async-LDS staging =====
__global__ __launch_bounds__(256, 2)
void k1_qk(const unsigned short* __restrict__ Htb, const unsigned short* __restrict__ WqkT,
           const float* __restrict__ bias, unsigned short* __restrict__ Q,
           unsigned short* __restrict__ Ko) {
  __shared__ unsigned short As[128 * 32];
  __shared__ unsigned short Bs[128 * 32];
  const int tid = threadIdx.x;
  const int row0 = blockIdx.y * 128, col0 = blockIdx.x * 128;
  const int w = tid >> 6, lane = tid & 63;
  const int wy = w >> 1, wx = w & 1, l16 = lane & 15, quad = lane >> 4;
  floatx4 acc[4][4];
#pragma unroll
  for (int i = 0; i < 4; i++)
#pragma unroll
    for (int j = 0; j < 4; j++)
#pragma unroll
      for (int r = 0; r < 4; r++) acc[i][j][r] = 0.f;

  for (int k0 = 0; k0 < TD; k0 += 32) {
    stage_gll(Htb, TD, row0, k0, w, lane, As);
    stage_gll(WqkT, TD, col0, k0, w, lane, Bs);
    __syncthreads();
    mfma_step_lin(As, Bs, wy, wx, l16, quad, acc);
    __syncthreads();
  }
#pragma unroll
  for (int i = 0; i < 4; i++)
#pragma unroll
    for (int j = 0; j < 4; j++) {
      const int col = col0 + wx * 64 + j * 16 + l16;
      const float bs = bias[col];
#pragma unroll
      for (int r = 0; r < 4; r++) {
        const int row = row0 + wy * 64 + i * 16 + quad * 4 + r;
        const float v = acc[i][j][r] + bs;
        if (col < TD) Q[(size_t)row * TD + col] = f2bf(v);
        else          Ko[(size_t)row * TD + (col - TD)] = f2bf(v);
      }
    }
}

// ==== K2 (R17): R9 two-pass no-max softmax + 2-head batching per iteration ==
// The h-loop body is too large to unroll, so head h+1's loads could not issue
// until head h's serial tail retired. Batching 2 heads doubles load/MFMA/
// shuffle ILP per iteration. Per-value FP order preserved -> bit-identical.
#define OB_S 520
__global__ __launch_bounds__(256, 2)
void k2_attn(const unsigned short* __restrict__ Q, const unsigned short* __restrict__ Kb,
             const float* __restrict__ Ml, const float* __restrict__ am,
             unsigned short* __restrict__ Am) {
  // LDS plan (1040 float4 = 16640 B):
  //   [0, 768)   part[h][q][wave] float4 {Z,d0,d1,d2}   (pass 1)
  //   [768, 960) wlds[h][q] float4 {w0,w1,w2,-}         (pass 2)
  //   epilogue: obuf (16*OB_S ushorts = 16640 B) overlays everything
  __shared__ float4 ldsf4[1040];
  const int i0 = blockIdx.x;
  const int xcd = i0 & 7, jj = i0 >> 3;
  const int b = xcd + 8 * (jj & 1);
  const int q0 = (jj >> 1) * 16;
  const int tid = threadIdx.x;
  const int w = tid >> 6, lane = tid & 63;
  const int l16 = lane & 15, quad = lane >> 4;
  const int kbase = w * 128;

  const float* amb = am + b * TS;
  float amq[4], amk[8], maskv[8];
#pragma unroll
  for (int r = 0; r < 4; r++) amq[r] = amb[q0 + quad * 4 + r];
#pragma unroll
  for (int kt = 0; kt < 8; kt++) {
    amk[kt] = amb[kbase + kt * 16 + l16];
    maskv[kt] = (1.f - amk[kt]) * (-1e9f);
  }

  unsigned Mpk[TNCH][4][4];
#pragma unroll
  for (int i = 0; i < TNCH; i++)
#pragma unroll
    for (int r = 0; r < 4; r++) {
      const float* Mrow = Ml + ((size_t)((b * TNCH + i) * TS + q0 + quad * 4 + r)) * TS;
#pragma unroll
      for (int kt2 = 0; kt2 < 4; kt2++) {
        const int ke = kbase + kt2 * 32 + l16;
        const float me = Mrow[ke] * amk[kt2 * 2] * amq[r];
        const float mo = Mrow[ke + 16] * amk[kt2 * 2 + 1] * amq[r];
        Mpk[i][r][kt2] = f2bf2(me, mo);
      }
    }

  const unsigned short* qbase = Q + ((size_t)(b * TS + q0 + l16)) * TD + quad * 8;
  const unsigned short* kb0   = Kb + ((size_t)(b * TS + kbase + l16)) * TD + quad * 8;

  // ------------- pass 1: denominators only, 2 heads per iteration ----------
  for (int hp = 0; hp < TH; hp += 2) {
    floatx4 sacc[2][8];
#pragma unroll
    for (int hh = 0; hh < 2; hh++)
#pragma unroll
      for (int kt = 0; kt < 8; kt++)
#pragma unroll
        for (int r = 0; r < 4; r++) sacc[hh][kt][r] = 0.f;
#pragma unroll
    for (int dk = 0; dk < 2; dk++) {
      U4 a0, a1;
      a0.u = *(const uint4*)(qbase + hp * TDH + dk * 32);
      a1.u = *(const uint4*)(qbase + (hp + 1) * TDH + dk * 32);
#pragma unroll
      for (int kt = 0; kt < 8; kt++) {
        const unsigned short* kp = kb0 + (size_t)kt * 16 * TD + hp * TDH + dk * 32;
        U4 b0; b0.u = *(const uint4*)kp;
        U4 b1; b1.u = *(const uint4*)(kp + TDH);
        sacc[0][kt] = __builtin_amdgcn_mfma_f32_16x16x32_bf16(a0.s, b0.s, sacc[0][kt], 0, 0, 0);
        sacc[1][kt] = __builtin_amdgcn_mfma_f32_16x16x32_bf16(a1.s, b1.s, sacc[1][kt], 0, 0, 0);
      }
    }
    float e[2][8][4];
    float Zp[2][4];
    float dmp[2][TNCH][4];
#pragma unroll
    for (int hh = 0; hh < 2; hh++) {
#pragma unroll
      for (int r = 0; r < 4; r++) Zp[hh][r] = 0.f;
#pragma unroll
      for (int kt = 0; kt < 8; kt++)
#pragma unroll
        for (int r = 0; r < 4; r++) {
          const float v = __expf(sacc[hh][kt][r] * SCALE + maskv[kt]);
          e[hh][kt][r] = v;
          Zp[hh][r] += v;
        }
#pragma unroll
      for (int i = 0; i < TNCH; i++)
#pragma unroll
        for (int r = 0; r < 4; r++) {
          float d = 0.f;
#pragma unroll
          for (int kt2 = 0; kt2 < 4; kt2++) {
            const unsigned u = Mpk[i][r][kt2];
            d += __uint_as_float(u << 16) * e[hh][kt2 * 2][r];
            d += __uint_as_float(u & 0xffff0000u) * e[hh][kt2 * 2 + 1][r];
          }
          dmp[hh][i][r] = d;
        }
    }
#pragma unroll
    for (int r = 0; r < 4; r++) {
#pragma unroll
      for (int off = 1; off < 16; off <<= 1) {
#pragma unroll
        for (int hh = 0; hh < 2; hh++) {
          Zp[hh][r] += __shfl_xor(Zp[hh][r], off);
          dmp[hh][0][r] += __shfl_xor(dmp[hh][0][r], off);
          dmp[hh][1][r] += __shfl_xor(dmp[hh][1][r], off);
          dmp[hh][2][r] += __shfl_xor(dmp[hh][2][r], off);
        }
      }
    }
    if (l16 == 0) {
#pragma unroll
      for (int hh = 0; hh < 2; hh++)
#pragma unroll
        for (int r = 0; r < 4; r++)
          ldsf4[((hp + hh) * 16 + quad * 4 + r) * 4 + w] =
              make_float4(Zp[hh][r], dmp[hh][0][r], dmp[hh][1][r], dmp[hh][2][r]);
    }
  }
  __syncthreads();

  // ---------------- reduce partials -> per-(h,q) channel weights -----------
  if (tid < TH * 16) {
    const int h = tid >> 4, q = tid & 15;
    const int base = (h * 16 + q) * 4;
    const float4 p0 = ldsf4[base + 0];
    const float4 p1 = ldsf4[base + 1];
    const float4 p2 = ldsf4[base + 2];
    const float4 p3 = ldsf4[base + 3];
    const float Z  = p0.x + p1.x + p2.x + p3.x;
    const float d0 = p0.y + p1.y + p2.y + p3.y;
    const float d1 = p0.z + p1.z + p2.z + p3.z;
    const float d2 = p0.w + p1.w + p2.w + p3.w;
    const float ez = 1e-10f * Z + 1e-30f;
    ldsf4[768 + h * 16 + q] =
        make_float4(1.f / (d0 + ez), 1.f / (d1 + ez), 1.f / (d2 + ez), 0.f);
  }
  __syncthreads();

  // ------------- pass 2: recompute e, accumulate; 2 heads per iter ---------
  float acc[TNCH][8][4];
#pragma unroll
  for (int i = 0; i < TNCH; i++)
#pragma unroll
    for (int kt = 0; kt < 8; kt++)
#pragma unroll
      for (int r = 0; r < 4; r++) acc[i][kt][r] = 0.f;

  for (int hp = 0; hp < TH; hp += 2) {
    floatx4 sacc[2][8];
#pragma unroll
    for (int hh = 0; hh < 2; hh++)
#pragma unroll
      for (int kt = 0; kt < 8; kt++)
#pragma unroll
        for (int r = 0; r < 4; r++) sacc[hh][kt][r] = 0.f;
#pragma unroll
    for (int dk = 0; dk < 2; dk++) {
      U4 a0, a1;
      a0.u = *(const uint4*)(qbase + hp * TDH + dk * 32);
      a1.u = *(const uint4*)(qbase + (hp + 1) * TDH + dk * 32);
#pragma unroll
      for (int kt = 0; kt < 8; kt++) {
        const unsigned short* kp = kb0 + (size_t)kt * 16 * TD + hp * TDH + dk * 32;
        U4 b0; b0.u = *(const uint4*)kp;
        U4 b1; b1.u = *(const uint4*)(kp + TDH);
        sacc[0][kt] = __builtin_amdgcn_mfma_f32_16x16x32_bf16(a0.s, b0.s, sacc[0][kt], 0, 0, 0);
        sacc[1][kt] = __builtin_amdgcn_mfma_f32_16x16x32_bf16(a1.s, b1.s, sacc[1][kt], 0, 0, 0);
      }
    }
#pragma unroll
    for (int hh = 0; hh < 2; hh++) {
      float4 wv[4];
#pragma unroll
      for (int r = 0; r < 4; r++) wv[r] = ldsf4[768 + (hp + hh) * 16 + quad * 4 + r];
#pragma unroll
      for (int kt = 0; kt < 8; kt++)
#pragma unroll
        for (int r = 0; r < 4; r++) {
          const float v = __expf(sacc[hh][kt][r] * SCALE + maskv[kt]);
          acc[0][kt][r] += v * wv[r].x;
          acc[1][kt][r] += v * wv[r].y;
          acc[2][kt][r] += v * wv[r].z;
        }
    }
  }
  __syncthreads();   // protect obuf overlay of part/wlds

  // ---------------- epilogue: Am = bf16(M * acc / 12), staged via LDS ------
  unsigned short* obuf = (unsigned short*)ldsf4;
  const float inv_h = 1.f / (float)TH;
  for (int i = 0; i < TNCH; i++) {
#pragma unroll
    for (int r = 0; r < 4; r++) {
      const int q = q0 + quad * 4 + r;
      const float* Mrow = Ml + ((size_t)((b * TNCH + i) * TS + q)) * TS;
#pragma unroll
      for (int kt = 0; kt < 8; kt++) {
        const int k = kbase + kt * 16 + l16;
        const float mv = Mrow[k] * amk[kt] * amq[r];
        obuf[(quad * 4 + r) * OB_S + k] = f2bf(mv * acc[i][kt][r] * inv_h);
      }
    }
    __syncthreads();
#pragma unroll
    for (int it = 0; it < 4; it++) {
      const int idx = tid + it * 256;
      const int row = idx >> 6, c16 = idx & 63;
      const uint4 v = *(const uint4*)&obuf[row * OB_S + c16 * 8];
      *(uint4*)&Am[((size_t)((i * TB + b) * TS + q0 + row)) * TS + c16 * 8] = v;
    }
    __syncthreads();
  }
}

// ===== K3: G[z] = Am[z] @ HtbT[b]^T -> bf16, async-LDS staging =====
__global__ __launch_bounds__(256, 2)
void k3_feat(const unsigned short* __restrict__ Am, const unsigned short* __restrict__ HtbT,
             unsigned short* __restrict__ G) {
  __shared__ unsigned short As[128 * 32];
  __shared__ unsigned short Bs[128 * 32];
  const int z = blockIdx.z;
  const int b = z & 15;
  const unsigned short* A  = Am + (size_t)z * TS * TS;
  const unsigned short* Bt = HtbT + (size_t)b * TD * TS;
  unsigned short* C = G + (size_t)z * TS * TD;
  const int tid = threadIdx.x;
  const int row0 = blockIdx.y * 128, col0 = blockIdx.x * 128;
  const int w = tid >> 6, lane = tid & 63;
  const int wy = w >> 1, wx = w & 1, l16 = lane & 15, quad = lane >> 4;
  floatx4 acc[4][4];
#pragma unroll
  for (int i = 0; i < 4; i++)
#pragma unroll
    for (int j = 0; j < 4; j++)
#pragma unroll
      for (int r = 0; r < 4; r++) acc[i][j][r] = 0.f;

  for (int k0 = 0; k0 < TS; k0 += 32) {
    stage_gll(A, TS, row0, k0, w, lane, As);
    stage_gll(Bt, TS, col0, k0, w, lane, Bs);
    __syncthreads();
    mfma_step_lin(As, Bs, wy, wx, l16, quad, acc);
    __syncthreads();
  }
#pragma unroll
  for (int i = 0; i < 4; i++)
#pragma unroll
    for (int j = 0; j < 4; j++) {
      const int col = col0 + wx * 64 + j * 16 + l16;
#pragma unroll
      for (int r = 0; r < 4; r++) {
        const int row = row0 + wy * 64 + i * 16 + quad * 4 + r;
        C[(size_t)row * TD + col] = f2bf(acc[i][j][r]);
      }
    }
}

// == K4 (R6 form): out = mean_ch relu(G_ch @ WgT_ch^T + bg_ch) * am ==========
__global__ __launch_bounds__(256, 2)
void k4_out(const unsigned short* __restrict__ G, const unsigned short* __restrict__ WgT,
            const float* __restrict__ bg, const float* __restrict__ am,
            float* __restrict__ out) {
  __shared__ unsigned short As[128 * 32];
  __shared__ unsigned short Bs[128 * 32];
  const int tid = threadIdx.x;
  const int row0 = blockIdx.y * 128, col0 = blockIdx.x * 128;
  const int w = tid >> 6, lane = tid & 63;
  const int wy = w >> 1, wx = w & 1, l16 = lane & 15, quad = lane >> 4;
  float osum[4][4][4];
#pragma unroll
  for (int i = 0; i < 4; i++)
#pragma unroll
    for (int j = 0; j < 4; j++)
#pragma unroll
      for (int r = 0; r < 4; r++) osum[i][j][r] = 0.f;

  for (int ch = 0; ch < TNCH; ch++) {
    const unsigned short* A  = G + (size_t)ch * (TB * TS) * TD;
    const unsigned short* Bt = WgT + (size_t)ch * TD * TD;
    floatx4 acc[4][4];
#pragma unroll
    for (int i = 0; i < 4; i++)
#pragma unroll
      for (int j = 0; j < 4; j++)
#pragma unroll
        for (int r = 0; r < 4; r++) acc[i][j][r] = 0.f;

    for (int k0 = 0; k0 < TD; k0 += 32) {
      stage_gll(A, TD, row0, k0, w, lane, As);
      stage_gll(Bt, TD, col0, k0, w, lane, Bs);
      __syncthreads();
      mfma_step_lin(As, Bs, wy, wx, l16, quad, acc);
      __syncthreads();
    }
#pragma unroll
    for (int i = 0; i < 4; i++)
#pragma unroll
      for (int j = 0; j < 4; j++) {
        const int col = col0 + wx * 64 + j * 16 + l16;
        const float bs = bg[ch * TD + col];
#pragma unroll
        for (int r = 0; r < 4; r++)
          osum[i][j][r] += fmaxf(acc[i][j][r] + bs, 0.f);
      }
  }
#pragma unroll
  for (int i = 0; i < 4; i++)
#pragma unroll
    for (int r = 0; r < 4; r++) {
      const int row = row0 + wy * 64 + i * 16 + quad * 4 + r;
      const float amr = am[row] * (1.f / 3.f);
#pragma unroll
      for (int j = 0; j < 4; j++) {
        const int col = col0 + wx * 64 + j * 16 + l16;
        out[(size_t)row * TD + col] = osum[i][j][r] * amr;
      }
    }
}

extern "C" void kernel_launch(void* const* d_in, const int* in_sizes, int n_in,
                              void* d_out, int out_size, void* d_ws, size_t ws_size,
                              hipStream_t stream) {
  const float* Ht    = (const float*)d_in[0];
  const float* Ml    = (const float*)d_in[1];
  const float* am    = (const float*)d_in[2];
  const float* W_qk  = (const float*)d_in[3];
  const float* b_qk  = (const float*)d_in[4];
  const float* W_gat = (const float*)d_in[5];
  const float* b_gat = (const float*)d_in[6];
  float* out = (float*)d_out;

  // ws layout (ushorts):
  //   Q     [0,          6291456)
  //   K     [6291456,   12582912)
  //   Htb   [12582912,  18874368)   bf16(Ht), A-operand for k1
  //   HtbT  [18874368,  25165824)   per-b [768][512], B-operand for k3
  //   WqkT  [25165824,  26345472)   [1536][768]
  //   WgT   [26345472,  28114944)   [3][768][768]
  //   Am    [28114944,  40697856)
  //   G     [0,         18874368)   overlays Q/K/Htb (dead after k2/k1)
  unsigned short* base = (unsigned short*)d_ws;
  const size_t SEG = (size_t)TB * TS * TD;            // 6291456
  unsigned short* Q    = base;
  unsigned short* Kw   = base + SEG;
  unsigned short* Htb  = base + 2 * SEG;
  unsigned short* HtbT = base + 3 * SEG;
  unsigned short* WqkT = base + 4 * SEG;
  unsigned short* WgT  = WqkT + (size_t)TD * 2 * TD;
  unsigned short* Am   = WgT + (size_t)TNCH * TD * TD;
  unsigned short* G    = base;

  // prep: bf16 conversions + transposes (one-shot, ~100 MB traffic)
  pconv <<<dim3(3072), 256, 0, stream>>>(Ht, Htb);
  ptrans<<<dim3(24, 16, 16), 256, 0, stream>>>(Ht, HtbT, TS, TD);
  ptrans<<<dim3(48, 24, 1),  256, 0, stream>>>(W_qk, WqkT, TD, 2 * TD);
  ptrans<<<dim3(24, 24, 3),  256, 0, stream>>>(W_gat, WgT, TD, TD);

  k1_qk  <<<dim3(12, 64), 256, 0, stream>>>(Htb, WqkT, b_qk, Q, Kw);
  k2_attn<<<dim3(512), 256, 0, stream>>>(Q, Kw, Ml, am, Am);
  k3_feat<<<dim3(6, 4, 48), 256, 0, stream>>>(Am, HtbT, G);
  k4_out <<<dim3(6, 64), 256, 0, stream>>>(G, WgT, b_gat, am, out);
}

// Round 14
// 350.277 us; speedup vs baseline: 1.2289x; 1.0911x over previous
//
#include <hip/hip_runtime.h>
#include <math.h>

typedef __attribute__((ext_vector_type(8))) short short8;
typedef __attribute__((ext_vector_type(4))) float floatx4;

#define TB 16
#define TS 512
#define TD 768
#define TH 12
#define TDH 64
#define TNCH 3

#define SCALE 0.03608439182435161f  // 1/sqrt(768)

__device__ __forceinline__ unsigned short f2bf(float f) {
  unsigned u = __float_as_uint(f);
  u += 0x7fffu + ((u >> 16) & 1u);   // round-to-nearest-even
  return (unsigned short)(u >> 16);
}
__device__ __forceinline__ unsigned f2bf2(float lo, float hi) {
  return (unsigned)f2bf(lo) | ((unsigned)f2bf(hi) << 16);
}

union U4 { uint4 u; short8 s; };

// ===================== prep kernels (one-shot convert/transpose) ============
__global__ __launch_bounds__(256)
void pconv(const float* __restrict__ src, unsigned short* __restrict__ dst) {
  const int i = (blockIdx.x * 256 + threadIdx.x) * 8;
  const float4 a = *(const float4*)&src[i];
  const float4 b = *(const float4*)&src[i + 4];
  uint4 o;
  o.x = f2bf2(a.x, a.y); o.y = f2bf2(a.z, a.w);
  o.z = f2bf2(b.x, b.y); o.w = f2bf2(b.z, b.w);
  *(uint4*)&dst[i] = o;
}

__global__ __launch_bounds__(256)
void ptrans(const float* __restrict__ src, unsigned short* __restrict__ dst,
            int R, int C) {
  __shared__ float ts[32][33];
  const size_t zoff = (size_t)blockIdx.z * R * C;
  src += zoff; dst += zoff;
  const int c0 = blockIdx.x * 32, r0 = blockIdx.y * 32;
  const int x = threadIdx.x & 31, y = threadIdx.x >> 5;   // y in [0,8)
#pragma unroll
  for (int i = 0; i < 4; i++)
    ts[y + 8 * i][x] = src[(size_t)(r0 + y + 8 * i) * C + c0 + x];
  __syncthreads();
#pragma unroll
  for (int i = 0; i < 4; i++)
    dst[(size_t)(c0 + y + 8 * i) * R + r0 + x] = f2bf(ts[x][y + 8 * i]);
}

// ---- GEMM staging: async global->LDS, width 16, linear [128][32] (m97) ----
__device__ __forceinline__ void stage_gll(const unsigned short* __restrict__ S, int ld,
                                          int row0, int k0, int w, int lane,
                                          unsigned short* D) {
  const int rsub = lane >> 2, c = lane & 3;
#pragma unroll
  for (int i = 0; i < 2; i++) {
    const int r = w * 32 + i * 16;
    const unsigned short* g = &S[(size_t)(row0 + r + rsub) * ld + k0 + c * 8];
    unsigned short* d = &D[r * 32];
    __builtin_amdgcn_global_load_lds(
        (const __attribute__((address_space(1))) unsigned int*)(const void*)g,
        (__attribute__((address_space(3))) unsigned int*)(void*)d,
        16, 0, 0);
  }
}

__device__ __forceinline__ void mfma_step_lin(const unsigned short* As, const unsigned short* Bs,
                                              int wy, int wx, int l16, int quad,
                                              floatx4 acc[4][4]) {
  short8 af[4], bfr[4];
#pragma unroll
  for (int i = 0; i < 4; i++) {
    U4 t; t.u = *(const uint4*)&As[(wy * 64 + i * 16 + l16) * 32 + quad * 8];
    af[i] = t.s;
  }
#pragma unroll
  for (int j = 0; j < 4; j++) {
    U4 t; t.u = *(const uint4*)&Bs[(wx * 64 + j * 16 + l16) * 32 + quad * 8];
    bfr[j] = t.s;
  }
#pragma unroll
  for (int i = 0; i < 4; i++)
#pragma unroll
    for (int j = 0; j < 4; j++)
      acc[i][j] = __builtin_amdgcn_mfma_f32_16x16x32_bf16(af[i], bfr[j], acc[i][j], 0, 0, 0);
}

// == R18: XCD-aware chunked swizzle (T1). Consecutive tile ids (same row-
//    block, different col) land on ONE XCD -> row-panel becomes an L2 hit.
__device__ __forceinline__ int xcd_chunk(int bid, int cpx) {
  return (bid & 7) * cpx + (bid >> 3);
}

// ===== K1: qk = Htb @ WqkT^T + b_qk -> Q,K (bf16); 1D grid 768, swizzled ====
__global__ __launch_bounds__(256, 2)
void k1_qk(const unsigned short* __restrict__ Htb, const unsigned short* __restrict__ WqkT,
           const float* __restrict__ bias, unsigned short* __restrict__ Q,
           unsigned short* __restrict__ Ko) {
  __shared__ unsigned short As[128 * 32];
  __shared__ unsigned short Bs[128 * 32];
  const int tid = threadIdx.x;
  const int t = xcd_chunk(blockIdx.x, 96);        // 768 tiles, 96 per XCD
  const int row0 = (t / 12) * 128, col0 = (t % 12) * 128;
  const int w = tid >> 6, lane = tid & 63;
  const int wy = w >> 1, wx = w & 1, l16 = lane & 15, quad = lane >> 4;
  floatx4 acc[4][4];
#pragma unroll
  for (int i = 0; i < 4; i++)
#pragma unroll
    for (int j = 0; j < 4; j++)
#pragma unroll
      for (int r = 0; r < 4; r++) acc[i][j][r] = 0.f;

  for (int k0 = 0; k0 < TD; k0 += 32) {
    stage_gll(Htb, TD, row0, k0, w, lane, As);
    stage_gll(WqkT, TD, col0, k0, w, lane, Bs);
    __syncthreads();
    mfma_step_lin(As, Bs, wy, wx, l16, quad, acc);
    __syncthreads();
  }
#pragma unroll
  for (int i = 0; i < 4; i++)
#pragma unroll
    for (int j = 0; j < 4; j++) {
      const int col = col0 + wx * 64 + j * 16 + l16;
      const float bs = bias[col];
#pragma unroll
      for (int r = 0; r < 4; r++) {
        const int row = row0 + wy * 64 + i * 16 + quad * 4 + r;
        const float v = acc[i][j][r] + bs;
        if (col < TD) Q[(size_t)row * TD + col] = f2bf(v);
        else          Ko[(size_t)row * TD + (col - TD)] = f2bf(v);
      }
    }
}

// ==== K2: MFMA scores; no-max-sub two-pass softmax (R9 exact, 128 us) =======
#define OB_S 520
__global__ __launch_bounds__(256, 2)
void k2_attn(const unsigned short* __restrict__ Q, const unsigned short* __restrict__ Kb,
             const float* __restrict__ Ml, const float* __restrict__ am,
             unsigned short* __restrict__ Am) {
  // LDS plan (1040 float4 = 16640 B):
  //   [0, 768)   part[h][q][wave] float4 {Z,d0,d1,d2}   (pass 1)
  //   [768, 960) wlds[h][q] float4 {w0,w1,w2,-}         (pass 2)
  //   epilogue: obuf (16*OB_S ushorts = 16640 B) overlays everything
  __shared__ float4 ldsf4[1040];
  const int i0 = blockIdx.x;
  const int xcd = i0 & 7, jj = i0 >> 3;
  const int b = xcd + 8 * (jj & 1);
  const int q0 = (jj >> 1) * 16;
  const int tid = threadIdx.x;
  const int w = tid >> 6, lane = tid & 63;
  const int l16 = lane & 15, quad = lane >> 4;
  const int kbase = w * 128;

  const float* amb = am + b * TS;
  float amq[4], amk[8], maskv[8];
#pragma unroll
  for (int r = 0; r < 4; r++) amq[r] = amb[q0 + quad * 4 + r];
#pragma unroll
  for (int kt = 0; kt < 8; kt++) {
    amk[kt] = amb[kbase + kt * 16 + l16];
    maskv[kt] = (1.f - amk[kt]) * (-1e9f);
  }

  unsigned Mpk[TNCH][4][4];
#pragma unroll
  for (int i = 0; i < TNCH; i++)
#pragma unroll
    for (int r = 0; r < 4; r++) {
      const float* Mrow = Ml + ((size_t)((b * TNCH + i) * TS + q0 + quad * 4 + r)) * TS;
#pragma unroll
      for (int kt2 = 0; kt2 < 4; kt2++) {
        const int ke = kbase + kt2 * 32 + l16;
        const float me = Mrow[ke] * amk[kt2 * 2] * amq[r];
        const float mo = Mrow[ke + 16] * amk[kt2 * 2 + 1] * amq[r];
        Mpk[i][r][kt2] = f2bf2(me, mo);
      }
    }

  const unsigned short* qbase = Q + ((size_t)(b * TS + q0 + l16)) * TD + quad * 8;
  const unsigned short* kb0   = Kb + ((size_t)(b * TS + kbase + l16)) * TD + quad * 8;

  // ---------------- pass 1: denominators only (barrier-free loop) ----------
  for (int h = 0; h < TH; h++) {
    floatx4 sacc[8];
#pragma unroll
    for (int kt = 0; kt < 8; kt++)
#pragma unroll
      for (int r = 0; r < 4; r++) sacc[kt][r] = 0.f;
#pragma unroll
    for (int dk = 0; dk < 2; dk++) {
      U4 a; a.u = *(const uint4*)(qbase + h * TDH + dk * 32);
#pragma unroll
      for (int kt = 0; kt < 8; kt++) {
        U4 bb; bb.u = *(const uint4*)(kb0 + (size_t)kt * 16 * TD + h * TDH + dk * 32);
        sacc[kt] = __builtin_amdgcn_mfma_f32_16x16x32_bf16(a.s, bb.s, sacc[kt], 0, 0, 0);
      }
    }
    float e[8][4];
    float Zp[4] = {0.f, 0.f, 0.f, 0.f};
#pragma unroll
    for (int kt = 0; kt < 8; kt++)
#pragma unroll
      for (int r = 0; r < 4; r++) {
        const float v = __expf(sacc[kt][r] * SCALE + maskv[kt]);
        e[kt][r] = v;
        Zp[r] += v;
      }
    float dmp[TNCH][4];
#pragma unroll
    for (int i = 0; i < TNCH; i++)
#pragma unroll
      for (int r = 0; r < 4; r++) {
        float d = 0.f;
#pragma unroll
        for (int kt2 = 0; kt2 < 4; kt2++) {
          const unsigned u = Mpk[i][r][kt2];
          d += __uint_as_float(u << 16) * e[kt2 * 2][r];
          d += __uint_as_float(u & 0xffff0000u) * e[kt2 * 2 + 1][r];
        }
        dmp[i][r] = d;
      }
#pragma unroll
    for (int r = 0; r < 4; r++) {
#pragma unroll
      for (int off = 1; off < 16; off <<= 1) {
        Zp[r] += __shfl_xor(Zp[r], off);
        dmp[0][r] += __shfl_xor(dmp[0][r], off);
        dmp[1][r] += __shfl_xor(dmp[1][r], off);
        dmp[2][r] += __shfl_xor(dmp[2][r], off);
      }
    }
    if (l16 == 0) {
#pragma unroll
      for (int r = 0; r < 4; r++)
        ldsf4[(h * 16 + quad * 4 + r) * 4 + w] =
            make_float4(Zp[r], dmp[0][r], dmp[1][r], dmp[2][r]);
    }
  }
  __syncthreads();

  // ---------------- reduce partials -> per-(h,q) channel weights -----------
  if (tid < TH * 16) {
    const int h = tid >> 4, q = tid & 15;
    const int base = (h * 16 + q) * 4;
    const float4 p0 = ldsf4[base + 0];
    const float4 p1 = ldsf4[base + 1];
    const float4 p2 = ldsf4[base + 2];
    const float4 p3 = ldsf4[base + 3];
    const float Z  = p0.x + p1.x + p2.x + p3.x;
    const float d0 = p0.y + p1.y + p2.y + p3.y;
    const float d1 = p0.z + p1.z + p2.z + p3.z;
    const float d2 = p0.w + p1.w + p2.w + p3.w;
    const float ez = 1e-10f * Z + 1e-30f;
    ldsf4[768 + h * 16 + q] =
        make_float4(1.f / (d0 + ez), 1.f / (d1 + ez), 1.f / (d2 + ez), 0.f);
  }
  __syncthreads();

  // ---------------- pass 2: recompute e, accumulate (barrier-free loop) ----
  float acc[TNCH][8][4];
#pragma unroll
  for (int i = 0; i < TNCH; i++)
#pragma unroll
    for (int kt = 0; kt < 8; kt++)
#pragma unroll
      for (int r = 0; r < 4; r++) acc[i][kt][r] = 0.f;

  for (int h = 0; h < TH; h++) {
    floatx4 sacc[8];
#pragma unroll
    for (int kt = 0; kt < 8; kt++)
#pragma unroll
      for (int r = 0; r < 4; r++) sacc[kt][r] = 0.f;
#pragma unroll
    for (int dk = 0; dk < 2; dk++) {
      U4 a; a.u = *(const uint4*)(qbase + h * TDH + dk * 32);
#pragma unroll
      for (int kt = 0; kt < 8; kt++) {
        U4 bb; bb.u = *(const uint4*)(kb0 + (size_t)kt * 16 * TD + h * TDH + dk * 32);
        sacc[kt] = __builtin_amdgcn_mfma_f32_16x16x32_bf16(a.s, bb.s, sacc[kt], 0, 0, 0);
      }
    }
    float4 wv[4];
#pragma unroll
    for (int r = 0; r < 4; r++) wv[r] = ldsf4[768 + h * 16 + quad * 4 + r];
#pragma unroll
    for (int kt = 0; kt < 8; kt++)
#pragma unroll
      for (int r = 0; r < 4; r++) {
        const float v = __expf(sacc[kt][r] * SCALE + maskv[kt]);
        acc[0][kt][r] += v * wv[r].x;
        acc[1][kt][r] += v * wv[r].y;
        acc[2][kt][r] += v * wv[r].z;
      }
  }
  __syncthreads();   // protect obuf overlay of part/wlds

  // ---------------- epilogue: Am = bf16(M * acc / 12), staged via LDS ------
  unsigned short* obuf = (unsigned short*)ldsf4;
  const float inv_h = 1.f / (float)TH;
  for (int i = 0; i < TNCH; i++) {
#pragma unroll
    for (int r = 0; r < 4; r++) {
      const int q = q0 + quad * 4 + r;
      const float* Mrow = Ml + ((size_t)((b * TNCH + i) * TS + q)) * TS;
#pragma unroll
      for (int kt = 0; kt < 8; kt++) {
        const int k = kbase + kt * 16 + l16;
        const float mv = Mrow[k] * amk[kt] * amq[r];
        obuf[(quad * 4 + r) * OB_S + k] = f2bf(mv * acc[i][kt][r] * inv_h);
      }
    }
    __syncthreads();
#pragma unroll
    for (int it = 0; it < 4; it++) {
      const int idx = tid + it * 256;
      const int row = idx >> 6, c16 = idx & 63;
      const uint4 v = *(const uint4*)&obuf[row * OB_S + c16 * 8];
      *(uint4*)&Am[((size_t)((i * TB + b) * TS + q0 + row)) * TS + c16 * 8] = v;
    }
    __syncthreads();
  }
}

// ===== K3: G[z] = Am[z] @ HtbT[b]^T -> bf16; 1D grid 1152, swizzled =========
__global__ __launch_bounds__(256, 2)
void k3_feat(const unsigned short* __restrict__ Am, const unsigned short* __restrict__ HtbT,
             unsigned short* __restrict__ G) {
  __shared__ unsigned short As[128 * 32];
  __shared__ unsigned short Bs[128 * 32];
  const int t = xcd_chunk(blockIdx.x, 144);       // 1152 tiles, 144 per XCD
  const int z = t / 24;                           // 6 z-slices per XCD
  const int rc = t % 24;
  const int row0 = (rc / 6) * 128, col0 = (rc % 6) * 128;
  const int b = z & 15;
  const unsigned short* A  = Am + (size_t)z * TS * TS;
  const unsigned short* Bt = HtbT + (size_t)b * TD * TS;
  unsigned short* C = G + (size_t)z * TS * TD;
  const int tid = threadIdx.x;
  const int w = tid >> 6, lane = tid & 63;
  const int wy = w >> 1, wx = w & 1, l16 = lane & 15, quad = lane >> 4;
  floatx4 acc[4][4];
#pragma unroll
  for (int i = 0; i < 4; i++)
#pragma unroll
    for (int j = 0; j < 4; j++)
#pragma unroll
      for (int r = 0; r < 4; r++) acc[i][j][r] = 0.f;

  for (int k0 = 0; k0 < TS; k0 += 32) {
    stage_gll(A, TS, row0, k0, w, lane, As);
    stage_gll(Bt, TS, col0, k0, w, lane, Bs);
    __syncthreads();
    mfma_step_lin(As, Bs, wy, wx, l16, quad, acc);
    __syncthreads();
  }
#pragma unroll
  for (int i = 0; i < 4; i++)
#pragma unroll
    for (int j = 0; j < 4; j++) {
      const int col = col0 + wx * 64 + j * 16 + l16;
#pragma unroll
      for (int r = 0; r < 4; r++) {
        const int row = row0 + wy * 64 + i * 16 + quad * 4 + r;
        C[(size_t)row * TD + col] = f2bf(acc[i][j][r]);
      }
    }
}

// == K4: out = mean_ch relu(G_ch @ WgT_ch^T + bg_ch) * am; swizzled 1D 384 ===
__global__ __launch_bounds__(256, 2)
void k4_out(const unsigned short* __restrict__ G, const unsigned short* __restrict__ WgT,
            const float* __restrict__ bg, const float* __restrict__ am,
            float* __restrict__ out) {
  __shared__ unsigned short As[128 * 32];
  __shared__ unsigned short Bs[128 * 32];
  const int tid = threadIdx.x;
  const int t = xcd_chunk(blockIdx.x, 48);        // 384 tiles, 48 per XCD
  const int row0 = (t / 6) * 128, col0 = (t % 6) * 128;
  const int w = tid >> 6, lane = tid & 63;
  const int wy = w >> 1, wx = w & 1, l16 = lane & 15, quad = lane >> 4;
  float osum[4][4][4];
#pragma unroll
  for (int i = 0; i < 4; i++)
#pragma unroll
    for (int j = 0; j < 4; j++)
#pragma unroll
      for (int r = 0; r < 4; r++) osum[i][j][r] = 0.f;

  for (int ch = 0; ch < TNCH; ch++) {
    const unsigned short* A  = G + (size_t)ch * (TB * TS) * TD;
    const unsigned short* Bt = WgT + (size_t)ch * TD * TD;
    floatx4 acc[4][4];
#pragma unroll
    for (int i = 0; i < 4; i++)
#pragma unroll
      for (int j = 0; j < 4; j++)
#pragma unroll
        for (int r = 0; r < 4; r++) acc[i][j][r] = 0.f;

    for (int k0 = 0; k0 < TD; k0 += 32) {
      stage_gll(A, TD, row0, k0, w, lane, As);
      stage_gll(Bt, TD, col0, k0, w, lane, Bs);
      __syncthreads();
      mfma_step_lin(As, Bs, wy, wx, l16, quad, acc);
      __syncthreads();
    }
#pragma unroll
    for (int i = 0; i < 4; i++)
#pragma unroll
      for (int j = 0; j < 4; j++) {
        const int col = col0 + wx * 64 + j * 16 + l16;
        const float bs = bg[ch * TD + col];
#pragma unroll
        for (int r = 0; r < 4; r++)
          osum[i][j][r] += fmaxf(acc[i][j][r] + bs, 0.f);
      }
  }
#pragma unroll
  for (int i = 0; i < 4; i++)
#pragma unroll
    for (int r = 0; r < 4; r++) {
      const int row = row0 + wy * 64 + i * 16 + quad * 4 + r;
      const float amr = am[row] * (1.f / 3.f);
#pragma unroll
      for (int j = 0; j < 4; j++) {
        const int col = col0 + wx * 64 + j * 16 + l16;
        out[(size_t)row * TD + col] = osum[i][j][r] * amr;
      }
    }
}

extern "C" void kernel_launch(void* const* d_in, const int* in_sizes, int n_in,
                              void* d_out, int out_size, void* d_ws, size_t ws_size,
                              hipStream_t stream) {
  const float* Ht    = (const float*)d_in[0];
  const float* Ml    = (const float*)d_in[1];
  const float* am    = (const float*)d_in[2];
  const float* W_qk  = (const float*)d_in[3];
  const float* b_qk  = (const float*)d_in[4];
  const float* W_gat = (const float*)d_in[5];
  const float* b_gat = (const float*)d_in[6];
  float* out = (float*)d_out;

  // ws layout (ushorts):
  //   Q     [0,          6291456)
  //   K     [6291456,   12582912)
  //   Htb   [12582912,  18874368)   bf16(Ht), A-operand for k1
  //   HtbT  [18874368,  25165824)   per-b [768][512], B-operand for k3
  //   WqkT  [25165824,  26345472)   [1536][768]
  //   WgT   [26345472,  28114944)   [3][768][768]
  //   Am    [28114944,  40697856)
  //   G     [0,         18874368)   overlays Q/K/Htb (dead after k2/k1)
  unsigned short* base = (unsigned short*)d_ws;
  const size_t SEG = (size_t)TB * TS * TD;            // 6291456
  unsigned short* Q    = base;
  unsigned short* Kw   = base + SEG;
  unsigned short* Htb  = base + 2 * SEG;
  unsigned short* HtbT = base + 3 * SEG;
  unsigned short* WqkT = base + 4 * SEG;
  unsigned short* WgT  = WqkT + (size_t)TD * 2 * TD;
  unsigned short* Am   = WgT + (size_t)TNCH * TD * TD;
  unsigned short* G    = base;

  // prep: bf16 conversions + transposes (one-shot, ~100 MB traffic)
  pconv <<<dim3(3072), 256, 0, stream>>>(Ht, Htb);
  ptrans<<<dim3(24, 16, 16), 256, 0, stream>>>(Ht, HtbT, TS, TD);
  ptrans<<<dim3(48, 24, 1),  256, 0, stream>>>(W_qk, WqkT, TD, 2 * TD);
  ptrans<<<dim3(24, 24, 3),  256, 0, stream>>>(W_gat, WgT, TD, TD);

  k1_qk  <<<dim3(768),  256, 0, stream>>>(Htb, WqkT, b_qk, Q, Kw);
  k2_attn<<<dim3(512),  256, 0, stream>>>(Q, Kw, Ml, am, Am);
  k3_feat<<<dim3(1152), 256, 0, stream>>>(Am, HtbT, G);
  k4_out <<<dim3(384),  256, 0, stream>>>(G, WgT, b_gat, am, out);
}

// Round 15
// 344.345 us; speedup vs baseline: 1.2500x; 1.0172x over previous
//
#include <hip/hip_runtime.h>
#include <math.h>

typedef __attribute__((ext_vector_type(8))) short short8;
typedef __attribute__((ext_vector_type(4))) float floatx4;

#define TB 16
#define TS 512
#define TD 768
#define TH 12
#define TDH 64
#define TNCH 3

#define SCALE 0.03608439182435161f  // 1/sqrt(768)

__device__ __forceinline__ unsigned short f2bf(float f) {
  unsigned u = __float_as_uint(f);
  u += 0x7fffu + ((u >> 16) & 1u);   // round-to-nearest-even
  return (unsigned short)(u >> 16);
}
__device__ __forceinline__ unsigned f2bf2(float lo, float hi) {
  return (unsigned)f2bf(lo) | ((unsigned)f2bf(hi) << 16);
}

union U4 { uint4 u; short8 s; };

// ========== prep: fused bf16-convert + transpose for Ht (reads Ht once) =====
// per 32x32 tile: write row-major bf16 (Htb) + transposed bf16 (HtbT).
__global__ __launch_bounds__(256)
void pfuse(const float* __restrict__ src, unsigned short* __restrict__ drm,
           unsigned short* __restrict__ dtr, int R, int C) {
  __shared__ float ts[32][33];
  const size_t zoff = (size_t)blockIdx.z * R * C;
  src += zoff; drm += zoff; dtr += zoff;
  const int c0 = blockIdx.x * 32, r0 = blockIdx.y * 32;
  const int x = threadIdx.x & 31, y = threadIdx.x >> 5;   // y in [0,8)
#pragma unroll
  for (int i = 0; i < 4; i++) {
    const float v = src[(size_t)(r0 + y + 8 * i) * C + c0 + x];
    ts[y + 8 * i][x] = v;
    drm[(size_t)(r0 + y + 8 * i) * C + c0 + x] = f2bf(v);
  }
  __syncthreads();
#pragma unroll
  for (int i = 0; i < 4; i++)
    dtr[(size_t)(c0 + y + 8 * i) * R + r0 + x] = f2bf(ts[x][y + 8 * i]);
}

// ptrans: per-z src [R][C] f32 -> dst [C][R] bf16 (weights)
__global__ __launch_bounds__(256)
void ptrans(const float* __restrict__ src, unsigned short* __restrict__ dst,
            int R, int C) {
  __shared__ float ts[32][33];
  const size_t zoff = (size_t)blockIdx.z * R * C;
  src += zoff; dst += zoff;
  const int c0 = blockIdx.x * 32, r0 = blockIdx.y * 32;
  const int x = threadIdx.x & 31, y = threadIdx.x >> 5;
#pragma unroll
  for (int i = 0; i < 4; i++)
    ts[y + 8 * i][x] = src[(size_t)(r0 + y + 8 * i) * C + c0 + x];
  __syncthreads();
#pragma unroll
  for (int i = 0; i < 4; i++)
    dst[(size_t)(c0 + y + 8 * i) * R + r0 + x] = f2bf(ts[x][y + 8 * i]);
}

// ---- GEMM staging: async global->LDS, width 16, linear [128][32] (m97) ----
__device__ __forceinline__ void stage_gll(const unsigned short* __restrict__ S, int ld,
                                          int row0, int k0, int w, int lane,
                                          unsigned short* D) {
  const int rsub = lane >> 2, c = lane & 3;
#pragma unroll
  for (int i = 0; i < 2; i++) {
    const int r = w * 32 + i * 16;
    const unsigned short* g = &S[(size_t)(row0 + r + rsub) * ld + k0 + c * 8];
    unsigned short* d = &D[r * 32];
    __builtin_amdgcn_global_load_lds(
        (const __attribute__((address_space(1))) unsigned int*)(const void*)g,
        (__attribute__((address_space(3))) unsigned int*)(void*)d,
        16, 0, 0);
  }
}

__device__ __forceinline__ void mfma_step_lin(const unsigned short* As, const unsigned short* Bs,
                                              int wy, int wx, int l16, int quad,
                                              floatx4 acc[4][4]) {
  short8 af[4], bfr[4];
#pragma unroll
  for (int i = 0; i < 4; i++) {
    U4 t; t.u = *(const uint4*)&As[(wy * 64 + i * 16 + l16) * 32 + quad * 8];
    af[i] = t.s;
  }
#pragma unroll
  for (int j = 0; j < 4; j++) {
    U4 t; t.u = *(const uint4*)&Bs[(wx * 64 + j * 16 + l16) * 32 + quad * 8];
    bfr[j] = t.s;
  }
#pragma unroll
  for (int i = 0; i < 4; i++)
#pragma unroll
    for (int j = 0; j < 4; j++)
      acc[i][j] = __builtin_amdgcn_mfma_f32_16x16x32_bf16(af[i], bfr[j], acc[i][j], 0, 0, 0);
}

// == XCD-aware chunked swizzle (T1, verified R18: -29 us) ====================
__device__ __forceinline__ int xcd_chunk(int bid, int cpx) {
  return (bid & 7) * cpx + (bid >> 3);
}

// ===== K1: qk = Htb @ WqkT^T + b_qk; paired k-steps (1 drain per 64-k) ======
__global__ __launch_bounds__(256, 2)
void k1_qk(const unsigned short* __restrict__ Htb, const unsigned short* __restrict__ WqkT,
           const float* __restrict__ bias, unsigned short* __restrict__ Q,
           unsigned short* __restrict__ Ko) {
  __shared__ unsigned short As0[128 * 32], As1[128 * 32];
  __shared__ unsigned short Bs0[128 * 32], Bs1[128 * 32];
  const int tid = threadIdx.x;
  const int t = xcd_chunk(blockIdx.x, 96);        // 768 tiles, 96 per XCD
  const int row0 = (t / 12) * 128, col0 = (t % 12) * 128;
  const int w = tid >> 6, lane = tid & 63;
  const int wy = w >> 1, wx = w & 1, l16 = lane & 15, quad = lane >> 4;
  floatx4 acc[4][4];
#pragma unroll
  for (int i = 0; i < 4; i++)
#pragma unroll
    for (int j = 0; j < 4; j++)
#pragma unroll
      for (int r = 0; r < 4; r++) acc[i][j][r] = 0.f;

  for (int k0 = 0; k0 < TD; k0 += 64) {
    stage_gll(Htb, TD, row0, k0, w, lane, As0);
    stage_gll(WqkT, TD, col0, k0, w, lane, Bs0);
    stage_gll(Htb, TD, row0, k0 + 32, w, lane, As1);
    stage_gll(WqkT, TD, col0, k0 + 32, w, lane, Bs1);
    __syncthreads();
    mfma_step_lin(As0, Bs0, wy, wx, l16, quad, acc);
    mfma_step_lin(As1, Bs1, wy, wx, l16, quad, acc);
    __syncthreads();
  }
#pragma unroll
  for (int i = 0; i < 4; i++)
#pragma unroll
    for (int j = 0; j < 4; j++) {
      const int col = col0 + wx * 64 + j * 16 + l16;
      const float bs = bias[col];
#pragma unroll
      for (int r = 0; r < 4; r++) {
        const int row = row0 + wy * 64 + i * 16 + quad * 4 + r;
        const float v = acc[i][j][r] + bs;
        if (col < TD) Q[(size_t)row * TD + col] = f2bf(v);
        else          Ko[(size_t)row * TD + (col - TD)] = f2bf(v);
      }
    }
}

// ==== K2: MFMA scores; no-max-sub two-pass softmax (R9 exact, 128 us) =======
#define OB_S 520
__global__ __launch_bounds__(256, 2)
void k2_attn(const unsigned short* __restrict__ Q, const unsigned short* __restrict__ Kb,
             const float* __restrict__ Ml, const float* __restrict__ am,
             unsigned short* __restrict__ Am) {
  __shared__ float4 ldsf4[1040];
  const int i0 = blockIdx.x;
  const int xcd = i0 & 7, jj = i0 >> 3;
  const int b = xcd + 8 * (jj & 1);
  const int q0 = (jj >> 1) * 16;
  const int tid = threadIdx.x;
  const int w = tid >> 6, lane = tid & 63;
  const int l16 = lane & 15, quad = lane >> 4;
  const int kbase = w * 128;

  const float* amb = am + b * TS;
  float amq[4], amk[8], maskv[8];
#pragma unroll
  for (int r = 0; r < 4; r++) amq[r] = amb[q0 + quad * 4 + r];
#pragma unroll
  for (int kt = 0; kt < 8; kt++) {
    amk[kt] = amb[kbase + kt * 16 + l16];
    maskv[kt] = (1.f - amk[kt]) * (-1e9f);
  }

  unsigned Mpk[TNCH][4][4];
#pragma unroll
  for (int i = 0; i < TNCH; i++)
#pragma unroll
    for (int r = 0; r < 4; r++) {
      const float* Mrow = Ml + ((size_t)((b * TNCH + i) * TS + q0 + quad * 4 + r)) * TS;
#pragma unroll
      for (int kt2 = 0; kt2 < 4; kt2++) {
        const int ke = kbase + kt2 * 32 + l16;
        const float me = Mrow[ke] * amk[kt2 * 2] * amq[r];
        const float mo = Mrow[ke + 16] * amk[kt2 * 2 + 1] * amq[r];
        Mpk[i][r][kt2] = f2bf2(me, mo);
      }
    }

  const unsigned short* qbase = Q + ((size_t)(b * TS + q0 + l16)) * TD + quad * 8;
  const unsigned short* kb0   = Kb + ((size_t)(b * TS + kbase + l16)) * TD + quad * 8;

  // ---------------- pass 1: denominators only (barrier-free loop) ----------
  for (int h = 0; h < TH; h++) {
    floatx4 sacc[8];
#pragma unroll
    for (int kt = 0; kt < 8; kt++)
#pragma unroll
      for (int r = 0; r < 4; r++) sacc[kt][r] = 0.f;
#pragma unroll
    for (int dk = 0; dk < 2; dk++) {
      U4 a; a.u = *(const uint4*)(qbase + h * TDH + dk * 32);
#pragma unroll
      for (int kt = 0; kt < 8; kt++) {
        U4 bb; bb.u = *(const uint4*)(kb0 + (size_t)kt * 16 * TD + h * TDH + dk * 32);
        sacc[kt] = __builtin_amdgcn_mfma_f32_16x16x32_bf16(a.s, bb.s, sacc[kt], 0, 0, 0);
      }
    }
    float e[8][4];
    float Zp[4] = {0.f, 0.f, 0.f, 0.f};
#pragma unroll
    for (int kt = 0; kt < 8; kt++)
#pragma unroll
      for (int r = 0; r < 4; r++) {
        const float v = __expf(sacc[kt][r] * SCALE + maskv[kt]);
        e[kt][r] = v;
        Zp[r] += v;
      }
    float dmp[TNCH][4];
#pragma unroll
    for (int i = 0; i < TNCH; i++)
#pragma unroll
      for (int r = 0; r < 4; r++) {
        float d = 0.f;
#pragma unroll
        for (int kt2 = 0; kt2 < 4; kt2++) {
          const unsigned u = Mpk[i][r][kt2];
          d += __uint_as_float(u << 16) * e[kt2 * 2][r];
          d += __uint_as_float(u & 0xffff0000u) * e[kt2 * 2 + 1][r];
        }
        dmp[i][r] = d;
      }
#pragma unroll
    for (int r = 0; r < 4; r++) {
#pragma unroll
      for (int off = 1; off < 16; off <<= 1) {
        Zp[r] += __shfl_xor(Zp[r], off);
        dmp[0][r] += __shfl_xor(dmp[0][r], off);
        dmp[1][r] += __shfl_xor(dmp[1][r], off);
        dmp[2][r] += __shfl_xor(dmp[2][r], off);
      }
    }
    if (l16 == 0) {
#pragma unroll
      for (int r = 0; r < 4; r++)
        ldsf4[(h * 16 + quad * 4 + r) * 4 + w] =
            make_float4(Zp[r], dmp[0][r], dmp[1][r], dmp[2][r]);
    }
  }
  __syncthreads();

  // ---------------- reduce partials -> per-(h,q) channel weights -----------
  if (tid < TH * 16) {
    const int h = tid >> 4, q = tid & 15;
    const int base = (h * 16 + q) * 4;
    const float4 p0 = ldsf4[base + 0];
    const float4 p1 = ldsf4[base + 1];
    const float4 p2 = ldsf4[base + 2];
    const float4 p3 = ldsf4[base + 3];
    const float Z  = p0.x + p1.x + p2.x + p3.x;
    const float d0 = p0.y + p1.y + p2.y + p3.y;
    const float d1 = p0.z + p1.z + p2.z + p3.z;
    const float d2 = p0.w + p1.w + p2.w + p3.w;
    const float ez = 1e-10f * Z + 1e-30f;
    ldsf4[768 + h * 16 + q] =
        make_float4(1.f / (d0 + ez), 1.f / (d1 + ez), 1.f / (d2 + ez), 0.f);
  }
  __syncthreads();

  // ---------------- pass 2: recompute e, accumulate (barrier-free loop) ----
  float acc[TNCH][8][4];
#pragma unroll
  for (int i = 0; i < TNCH; i++)
#pragma unroll
    for (int kt = 0; kt < 8; kt++)
#pragma unroll
      for (int r = 0; r < 4; r++) acc[i][kt][r] = 0.f;

  for (int h = 0; h < TH; h++) {
    floatx4 sacc[8];
#pragma unroll
    for (int kt = 0; kt < 8; kt++)
#pragma unroll
      for (int r = 0; r < 4; r++) sacc[kt][r] = 0.f;
#pragma unroll
    for (int dk = 0; dk < 2; dk++) {
      U4 a; a.u = *(const uint4*)(qbase + h * TDH + dk * 32);
#pragma unroll
      for (int kt = 0; kt < 8; kt++) {
        U4 bb; bb.u = *(const uint4*)(kb0 + (size_t)kt * 16 * TD + h * TDH + dk * 32);
        sacc[kt] = __builtin_amdgcn_mfma_f32_16x16x32_bf16(a.s, bb.s, sacc[kt], 0, 0, 0);
      }
    }
    float4 wv[4];
#pragma unroll
    for (int r = 0; r < 4; r++) wv[r] = ldsf4[768 + h * 16 + quad * 4 + r];
#pragma unroll
    for (int kt = 0; kt < 8; kt++)
#pragma unroll
      for (int r = 0; r < 4; r++) {
        const float v = __expf(sacc[kt][r] * SCALE + maskv[kt]);
        acc[0][kt][r] += v * wv[r].x;
        acc[1][kt][r] += v * wv[r].y;
        acc[2][kt][r] += v * wv[r].z;
      }
  }
  __syncthreads();   // protect obuf overlay of part/wlds

  // ---------------- epilogue: Am = bf16(M * acc / 12), staged via LDS ------
  unsigned short* obuf = (unsigned short*)ldsf4;
  const float inv_h = 1.f / (float)TH;
  for (int i = 0; i < TNCH; i++) {
#pragma unroll
    for (int r = 0; r < 4; r++) {
      const int q = q0 + quad * 4 + r;
      const float* Mrow = Ml + ((size_t)((b * TNCH + i) * TS + q)) * TS;
#pragma unroll
      for (int kt = 0; kt < 8; kt++) {
        const int k = kbase + kt * 16 + l16;
        const float mv = Mrow[k] * amk[kt] * amq[r];
        obuf[(quad * 4 + r) * OB_S + k] = f2bf(mv * acc[i][kt][r] * inv_h);
      }
    }
    __syncthreads();
#pragma unroll
    for (int it = 0; it < 4; it++) {
      const int idx = tid + it * 256;
      const int row = idx >> 6, c16 = idx & 63;
      const uint4 v = *(const uint4*)&obuf[row * OB_S + c16 * 8];
      *(uint4*)&Am[((size_t)((i * TB + b) * TS + q0 + row)) * TS + c16 * 8] = v;
    }
    __syncthreads();
  }
}

// ===== K3: G[z] = Am[z] @ HtbT[b]^T; paired k-steps, swizzled 1D 1152 =======
__global__ __launch_bounds__(256, 2)
void k3_feat(const unsigned short* __restrict__ Am, const unsigned short* __restrict__ HtbT,
             unsigned short* __restrict__ G) {
  __shared__ unsigned short As0[128 * 32], As1[128 * 32];
  __shared__ unsigned short Bs0[128 * 32], Bs1[128 * 32];
  const int t = xcd_chunk(blockIdx.x, 144);       // 1152 tiles, 144 per XCD
  const int z = t / 24;
  const int rc = t % 24;
  const int row0 = (rc / 6) * 128, col0 = (rc % 6) * 128;
  const int b = z & 15;
  const unsigned short* A  = Am + (size_t)z * TS * TS;
  const unsigned short* Bt = HtbT + (size_t)b * TD * TS;
  unsigned short* C = G + (size_t)z * TS * TD;
  const int tid = threadIdx.x;
  const int w = tid >> 6, lane = tid & 63;
  const int wy = w >> 1, wx = w & 1, l16 = lane & 15, quad = lane >> 4;
  floatx4 acc[4][4];
#pragma unroll
  for (int i = 0; i < 4; i++)
#pragma unroll
    for (int j = 0; j < 4; j++)
#pragma unroll
      for (int r = 0; r < 4; r++) acc[i][j][r] = 0.f;

  for (int k0 = 0; k0 < TS; k0 += 64) {
    stage_gll(A, TS, row0, k0, w, lane, As0);
    stage_gll(Bt, TS, col0, k0, w, lane, Bs0);
    stage_gll(A, TS, row0, k0 + 32, w, lane, As1);
    stage_gll(Bt, TS, col0, k0 + 32, w, lane, Bs1);
    __syncthreads();
    mfma_step_lin(As0, Bs0, wy, wx, l16, quad, acc);
    mfma_step_lin(As1, Bs1, wy, wx, l16, quad, acc);
    __syncthreads();
  }
#pragma unroll
  for (int i = 0; i < 4; i++)
#pragma unroll
    for (int j = 0; j < 4; j++) {
      const int col = col0 + wx * 64 + j * 16 + l16;
#pragma unroll
      for (int r = 0; r < 4; r++) {
        const int row = row0 + wy * 64 + i * 16 + quad * 4 + r;
        C[(size_t)row * TD + col] = f2bf(acc[i][j][r]);
      }
    }
}

// == K4: out = mean_ch relu(G_ch @ WgT_ch^T + bg_ch) * am; paired k-steps ====
__global__ __launch_bounds__(256, 2)
void k4_out(const unsigned short* __restrict__ G, const unsigned short* __restrict__ WgT,
            const float* __restrict__ bg, const float* __restrict__ am,
            float* __restrict__ out) {
  __shared__ unsigned short As0[128 * 32], As1[128 * 32];
  __shared__ unsigned short Bs0[128 * 32], Bs1[128 * 32];
  const int tid = threadIdx.x;
  const int t = xcd_chunk(blockIdx.x, 48);        // 384 tiles, 48 per XCD
  const int row0 = (t / 6) * 128, col0 = (t % 6) * 128;
  const int w = tid >> 6, lane = tid & 63;
  const int wy = w >> 1, wx = w & 1, l16 = lane & 15, quad = lane >> 4;
  float osum[4][4][4];
#pragma unroll
  for (int i = 0; i < 4; i++)
#pragma unroll
    for (int j = 0; j < 4; j++)
#pragma unroll
      for (int r = 0; r < 4; r++) osum[i][j][r] = 0.f;

  for (int ch = 0; ch < TNCH; ch++) {
    const unsigned short* A  = G + (size_t)ch * (TB * TS) * TD;
    const unsigned short* Bt = WgT + (size_t)ch * TD * TD;
    floatx4 acc[4][4];
#pragma unroll
    for (int i = 0; i < 4; i++)
#pragma unroll
      for (int j = 0; j < 4; j++)
#pragma unroll
        for (int r = 0; r < 4; r++) acc[i][j][r] = 0.f;

    for (int k0 = 0; k0 < TD; k0 += 64) {
      stage_gll(A, TD, row0, k0, w, lane, As0);
      stage_gll(Bt, TD, col0, k0, w, lane, Bs0);
      stage_gll(A, TD, row0, k0 + 32, w, lane, As1);
      stage_gll(Bt, TD, col0, k0 + 32, w, lane, Bs1);
      __syncthreads();
      mfma_step_lin(As0, Bs0, wy, wx, l16, quad, acc);
      mfma_step_lin(As1, Bs1, wy, wx, l16, quad, acc);
      __syncthreads();
    }
#pragma unroll
    for (int i = 0; i < 4; i++)
#pragma unroll
      for (int j = 0; j < 4; j++) {
        const int col = col0 + wx * 64 + j * 16 + l16;
        const float bs = bg[ch * TD + col];
#pragma unroll
        for (int r = 0; r < 4; r++)
          osum[i][j][r] += fmaxf(acc[i][j][r] + bs, 0.f);
      }
  }
#pragma unroll
  for (int i = 0; i < 4; i++)
#pragma unroll
    for (int r = 0; r < 4; r++) {
      const int row = row0 + wy * 64 + i * 16 + quad * 4 + r;
      const float amr = am[row] * (1.f / 3.f);
#pragma unroll
      for (int j = 0; j < 4; j++) {
        const int col = col0 + wx * 64 + j * 16 + l16;
        out[(size_t)row * TD + col] = osum[i][j][r] * amr;
      }
    }
}

extern "C" void kernel_launch(void* const* d_in, const int* in_sizes, int n_in,
                              void* d_out, int out_size, void* d_ws, size_t ws_size,
                              hipStream_t stream) {
  const float* Ht    = (const float*)d_in[0];
  const float* Ml    = (const float*)d_in[1];
  const float* am    = (const float*)d_in[2];
  const float* W_qk  = (const float*)d_in[3];
  const float* b_qk  = (const float*)d_in[4];
  const float* W_gat = (const float*)d_in[5];
  const float* b_gat = (const float*)d_in[6];
  float* out = (float*)d_out;

  // ws layout (ushorts):
  //   Q     [0,          6291456)
  //   K     [6291456,   12582912)
  //   Htb   [12582912,  18874368)   bf16(Ht), A-operand for k1
  //   HtbT  [18874368,  25165824)   per-b [768][512], B-operand for k3
  //   WqkT  [25165824,  26345472)   [1536][768]
  //   WgT   [26345472,  28114944)   [3][768][768]
  //   Am    [28114944,  40697856)
  //   G     [0,         18874368)   overlays Q/K/Htb (dead after k2/k1)
  unsigned short* base = (unsigned short*)d_ws;
  const size_t SEG = (size_t)TB * TS * TD;            // 6291456
  unsigned short* Q    = base;
  unsigned short* Kw   = base + SEG;
  unsigned short* Htb  = base + 2 * SEG;
  unsigned short* HtbT = base + 3 * SEG;
  unsigned short* WqkT = base + 4 * SEG;
  unsigned short* WgT  = WqkT + (size_t)TD * 2 * TD;
  unsigned short* Am   = WgT + (size_t)TNCH * TD * TD;
  unsigned short* G    = base;

  // prep: fused Ht convert+transpose (single Ht read) + weight transposes
  pfuse <<<dim3(24, 16, 16), 256, 0, stream>>>(Ht, Htb, HtbT, TS, TD);
  ptrans<<<dim3(48, 24, 1),  256, 0, stream>>>(W_qk, WqkT, TD, 2 * TD);
  ptrans<<<dim3(24, 24, 3),  256, 0, stream>>>(W_gat, WgT, TD, TD);

  k1_qk  <<<dim3(768),  256, 0, stream>>>(Htb, WqkT, b_qk, Q, Kw);
  k2_attn<<<dim3(512),  256, 0, stream>>>(Q, Kw, Ml, am, Am);
  k3_feat<<<dim3(1152), 256, 0, stream>>>(Am, HtbT, G);
  k4_out <<<dim3(384),  256, 0, stream>>>(G, WgT, b_gat, am, out);
}

// Round 16
// 331.257 us; speedup vs baseline: 1.2994x; 1.0395x over previous
//
#include <hip/hip_runtime.h>
#include <math.h>

typedef __attribute__((ext_vector_type(8))) short short8;
typedef __attribute__((ext_vector_type(4))) float floatx4;

#define TB 16
#define TS 512
#define TD 768
#define TH 12
#define TDH 64
#define TNCH 3

#define SCALE 0.03608439182435161f  // 1/sqrt(768)

__device__ __forceinline__ unsigned short f2bf(float f) {
  unsigned u = __float_as_uint(f);
  u += 0x7fffu + ((u >> 16) & 1u);   // round-to-nearest-even
  return (unsigned short)(u >> 16);
}
__device__ __forceinline__ unsigned f2bf2(float lo, float hi) {
  return (unsigned)f2bf(lo) | ((unsigned)f2bf(hi) << 16);
}

union U4 { uint4 u; short8 s; };

// ===================== prep kernels ========================================
__global__ __launch_bounds__(256)
void pconv(const float* __restrict__ src, unsigned short* __restrict__ dst) {
  const int i = (blockIdx.x * 256 + threadIdx.x) * 8;
  const float4 a = *(const float4*)&src[i];
  const float4 b = *(const float4*)&src[i + 4];
  uint4 o;
  o.x = f2bf2(a.x, a.y); o.y = f2bf2(a.z, a.w);
  o.z = f2bf2(b.x, b.y); o.w = f2bf2(b.z, b.w);
  *(uint4*)&dst[i] = o;
}

__global__ __launch_bounds__(256)
void ptrans(const float* __restrict__ src, unsigned short* __restrict__ dst,
            int R, int C) {
  __shared__ float ts[32][33];
  const size_t zoff = (size_t)blockIdx.z * R * C;
  src += zoff; dst += zoff;
  const int c0 = blockIdx.x * 32, r0 = blockIdx.y * 32;
  const int x = threadIdx.x & 31, y = threadIdx.x >> 5;
#pragma unroll
  for (int i = 0; i < 4; i++)
    ts[y + 8 * i][x] = src[(size_t)(r0 + y + 8 * i) * C + c0 + x];
  __syncthreads();
#pragma unroll
  for (int i = 0; i < 4; i++)
    dst[(size_t)(c0 + y + 8 * i) * R + r0 + x] = f2bf(ts[x][y + 8 * i]);
}

// ---- GEMM staging: async global->LDS, width 16, linear [128][32] (m97) ----
__device__ __forceinline__ void stage_gll(const unsigned short* __restrict__ S, int ld,
                                          int row0, int k0, int w, int lane,
                                          unsigned short* D) {
  const int rsub = lane >> 2, c = lane & 3;
#pragma unroll
  for (int i = 0; i < 2; i++) {
    const int r = w * 32 + i * 16;
    const unsigned short* g = &S[(size_t)(row0 + r + rsub) * ld + k0 + c * 8];
    unsigned short* d = &D[r * 32];
    __builtin_amdgcn_global_load_lds(
        (const __attribute__((address_space(1))) unsigned int*)(const void*)g,
        (__attribute__((address_space(3))) unsigned int*)(void*)d,
        16, 0, 0);
  }
}

__device__ __forceinline__ void mfma_step_lin(const unsigned short* As, const unsigned short* Bs,
                                              int wy, int wx, int l16, int quad,
                                              floatx4 acc[4][4]) {
  short8 af[4], bfr[4];
#pragma unroll
  for (int i = 0; i < 4; i++) {
    U4 t; t.u = *(const uint4*)&As[(wy * 64 + i * 16 + l16) * 32 + quad * 8];
    af[i] = t.s;
  }
#pragma unroll
  for (int j = 0; j < 4; j++) {
    U4 t; t.u = *(const uint4*)&Bs[(wx * 64 + j * 16 + l16) * 32 + quad * 8];
    bfr[j] = t.s;
  }
#pragma unroll
  for (int i = 0; i < 4; i++)
#pragma unroll
    for (int j = 0; j < 4; j++)
      acc[i][j] = __builtin_amdgcn_mfma_f32_16x16x32_bf16(af[i], bfr[j], acc[i][j], 0, 0, 0);
}

// == XCD-aware chunked swizzle (T1, verified: -29 us) ========================
__device__ __forceinline__ int xcd_chunk(int bid, int cpx) {
  return (bid & 7) * cpx + (bid >> 3);
}

// ===== K1: qk = Htb @ WqkT^T + b_qk; paired k-steps, swizzled ===============
__global__ __launch_bounds__(256, 2)
void k1_qk(const unsigned short* __restrict__ Htb, const unsigned short* __restrict__ WqkT,
           const float* __restrict__ bias, unsigned short* __restrict__ Q,
           unsigned short* __restrict__ Ko) {
  __shared__ unsigned short As0[128 * 32], As1[128 * 32];
  __shared__ unsigned short Bs0[128 * 32], Bs1[128 * 32];
  const int tid = threadIdx.x;
  const int t = xcd_chunk(blockIdx.x, 96);
  const int row0 = (t / 12) * 128, col0 = (t % 12) * 128;
  const int w = tid >> 6, lane = tid & 63;
  const int wy = w >> 1, wx = w & 1, l16 = lane & 15, quad = lane >> 4;
  floatx4 acc[4][4];
#pragma unroll
  for (int i = 0; i < 4; i++)
#pragma unroll
    for (int j = 0; j < 4; j++)
#pragma unroll
      for (int r = 0; r < 4; r++) acc[i][j][r] = 0.f;

  for (int k0 = 0; k0 < TD; k0 += 64) {
    stage_gll(Htb, TD, row0, k0, w, lane, As0);
    stage_gll(WqkT, TD, col0, k0, w, lane, Bs0);
    stage_gll(Htb, TD, row0, k0 + 32, w, lane, As1);
    stage_gll(WqkT, TD, col0, k0 + 32, w, lane, Bs1);
    __syncthreads();
    mfma_step_lin(As0, Bs0, wy, wx, l16, quad, acc);
    mfma_step_lin(As1, Bs1, wy, wx, l16, quad, acc);
    __syncthreads();
  }
#pragma unroll
  for (int i = 0; i < 4; i++)
#pragma unroll
    for (int j = 0; j < 4; j++) {
      const int col = col0 + wx * 64 + j * 16 + l16;
      const float bs = bias[col];
#pragma unroll
      for (int r = 0; r < 4; r++) {
        const int row = row0 + wy * 64 + i * 16 + quad * 4 + r;
        const float v = acc[i][j][r] + bs;
        if (col < TD) Q[(size_t)row * TD + col] = f2bf(v);
        else          Ko[(size_t)row * TD + (col - TD)] = f2bf(v);
      }
    }
}

// ==== K2: MFMA scores; no-max-sub two-pass softmax (R9 exact, 128 us) =======
#define OB_S 520
__global__ __launch_bounds__(256, 2)
void k2_attn(const unsigned short* __restrict__ Q, const unsigned short* __restrict__ Kb,
             const float* __restrict__ Ml, const float* __restrict__ am,
             unsigned short* __restrict__ Am) {
  __shared__ float4 ldsf4[1040];
  const int i0 = blockIdx.x;
  const int xcd = i0 & 7, jj = i0 >> 3;
  const int b = xcd + 8 * (jj & 1);
  const int q0 = (jj >> 1) * 16;
  const int tid = threadIdx.x;
  const int w = tid >> 6, lane = tid & 63;
  const int l16 = lane & 15, quad = lane >> 4;
  const int kbase = w * 128;

  const float* amb = am + b * TS;
  float amq[4], amk[8], maskv[8];
#pragma unroll
  for (int r = 0; r < 4; r++) amq[r] = amb[q0 + quad * 4 + r];
#pragma unroll
  for (int kt = 0; kt < 8; kt++) {
    amk[kt] = amb[kbase + kt * 16 + l16];
    maskv[kt] = (1.f - amk[kt]) * (-1e9f);
  }

  unsigned Mpk[TNCH][4][4];
#pragma unroll
  for (int i = 0; i < TNCH; i++)
#pragma unroll
    for (int r = 0; r < 4; r++) {
      const float* Mrow = Ml + ((size_t)((b * TNCH + i) * TS + q0 + quad * 4 + r)) * TS;
#pragma unroll
      for (int kt2 = 0; kt2 < 4; kt2++) {
        const int ke = kbase + kt2 * 32 + l16;
        const float me = Mrow[ke] * amk[kt2 * 2] * amq[r];
        const float mo = Mrow[ke + 16] * amk[kt2 * 2 + 1] * amq[r];
        Mpk[i][r][kt2] = f2bf2(me, mo);
      }
    }

  const unsigned short* qbase = Q + ((size_t)(b * TS + q0 + l16)) * TD + quad * 8;
  const unsigned short* kb0   = Kb + ((size_t)(b * TS + kbase + l16)) * TD + quad * 8;

  for (int h = 0; h < TH; h++) {
    floatx4 sacc[8];
#pragma unroll
    for (int kt = 0; kt < 8; kt++)
#pragma unroll
      for (int r = 0; r < 4; r++) sacc[kt][r] = 0.f;
#pragma unroll
    for (int dk = 0; dk < 2; dk++) {
      U4 a; a.u = *(const uint4*)(qbase + h * TDH + dk * 32);
#pragma unroll
      for (int kt = 0; kt < 8; kt++) {
        U4 bb; bb.u = *(const uint4*)(kb0 + (size_t)kt * 16 * TD + h * TDH + dk * 32);
        sacc[kt] = __builtin_amdgcn_mfma_f32_16x16x32_bf16(a.s, bb.s, sacc[kt], 0, 0, 0);
      }
    }
    float e[8][4];
    float Zp[4] = {0.f, 0.f, 0.f, 0.f};
#pragma unroll
    for (int kt = 0; kt < 8; kt++)
#pragma unroll
      for (int r = 0; r < 4; r++) {
        const float v = __expf(sacc[kt][r] * SCALE + maskv[kt]);
        e[kt][r] = v;
        Zp[r] += v;
      }
    float dmp[TNCH][4];
#pragma unroll
    for (int i = 0; i < TNCH; i++)
#pragma unroll
      for (int r = 0; r < 4; r++) {
        float d = 0.f;
#pragma unroll
        for (int kt2 = 0; kt2 < 4; kt2++) {
          const unsigned u = Mpk[i][r][kt2];
          d += __uint_as_float(u << 16) * e[kt2 * 2][r];
          d += __uint_as_float(u & 0xffff0000u) * e[kt2 * 2 + 1][r];
        }
        dmp[i][r] = d;
      }
#pragma unroll
    for (int r = 0; r < 4; r++) {
#pragma unroll
      for (int off = 1; off < 16; off <<= 1) {
        Zp[r] += __shfl_xor(Zp[r], off);
        dmp[0][r] += __shfl_xor(dmp[0][r], off);
        dmp[1][r] += __shfl_xor(dmp[1][r], off);
        dmp[2][r] += __shfl_xor(dmp[2][r], off);
      }
    }
    if (l16 == 0) {
#pragma unroll
      for (int r = 0; r < 4; r++)
        ldsf4[(h * 16 + quad * 4 + r) * 4 + w] =
            make_float4(Zp[r], dmp[0][r], dmp[1][r], dmp[2][r]);
    }
  }
  __syncthreads();

  if (tid < TH * 16) {
    const int h = tid >> 4, q = tid & 15;
    const int base = (h * 16 + q) * 4;
    const float4 p0 = ldsf4[base + 0];
    const float4 p1 = ldsf4[base + 1];
    const float4 p2 = ldsf4[base + 2];
    const float4 p3 = ldsf4[base + 3];
    const float Z  = p0.x + p1.x + p2.x + p3.x;
    const float d0 = p0.y + p1.y + p2.y + p3.y;
    const float d1 = p0.z + p1.z + p2.z + p3.z;
    const float d2 = p0.w + p1.w + p2.w + p3.w;
    const float ez = 1e-10f * Z + 1e-30f;
    ldsf4[768 + h * 16 + q] =
        make_float4(1.f / (d0 + ez), 1.f / (d1 + ez), 1.f / (d2 + ez), 0.f);
  }
  __syncthreads();

  float acc[TNCH][8][4];
#pragma unroll
  for (int i = 0; i < TNCH; i++)
#pragma unroll
    for (int kt = 0; kt < 8; kt++)
#pragma unroll
      for (int r = 0; r < 4; r++) acc[i][kt][r] = 0.f;

  for (int h = 0; h < TH; h++) {
    floatx4 sacc[8];
#pragma unroll
    for (int kt = 0; kt < 8; kt++)
#pragma unroll
      for (int r = 0; r < 4; r++) sacc[kt][r] = 0.f;
#pragma unroll
    for (int dk = 0; dk < 2; dk++) {
      U4 a; a.u = *(const uint4*)(qbase + h * TDH + dk * 32);
#pragma unroll
      for (int kt = 0; kt < 8; kt++) {
        U4 bb; bb.u = *(const uint4*)(kb0 + (size_t)kt * 16 * TD + h * TDH + dk * 32);
        sacc[kt] = __builtin_amdgcn_mfma_f32_16x16x32_bf16(a.s, bb.s, sacc[kt], 0, 0, 0);
      }
    }
    float4 wv[4];
#pragma unroll
    for (int r = 0; r < 4; r++) wv[r] = ldsf4[768 + h * 16 + quad * 4 + r];
#pragma unroll
    for (int kt = 0; kt < 8; kt++)
#pragma unroll
      for (int r = 0; r < 4; r++) {
        const float v = __expf(sacc[kt][r] * SCALE + maskv[kt]);
        acc[0][kt][r] += v * wv[r].x;
        acc[1][kt][r] += v * wv[r].y;
        acc[2][kt][r] += v * wv[r].z;
      }
  }
  __syncthreads();

  unsigned short* obuf = (unsigned short*)ldsf4;
  const float inv_h = 1.f / (float)TH;
  for (int i = 0; i < TNCH; i++) {
#pragma unroll
    for (int r = 0; r < 4; r++) {
      const int q = q0 + quad * 4 + r;
      const float* Mrow = Ml + ((size_t)((b * TNCH + i) * TS + q)) * TS;
#pragma unroll
      for (int kt = 0; kt < 8; kt++) {
        const int k = kbase + kt * 16 + l16;
        const float mv = Mrow[k] * amk[kt] * amq[r];
        obuf[(quad * 4 + r) * OB_S + k] = f2bf(mv * acc[i][kt][r] * inv_h);
      }
    }
    __syncthreads();
#pragma unroll
    for (int it = 0; it < 4; it++) {
      const int idx = tid + it * 256;
      const int row = idx >> 6, c16 = idx & 63;
      const uint4 v = *(const uint4*)&obuf[row * OB_S + c16 * 8];
      *(uint4*)&Am[((size_t)((i * TB + b) * TS + q0 + row)) * TS + c16 * 8] = v;
    }
    __syncthreads();
  }
}

// ===== K3n: HtW_ch = Htb @ WgT_ch^T, stored TRANSPOSED per (ch,b): [768][512]
// (A@Ht)@W == A@(Ht@W): kills the 118 MB G re-fetch in k4 (R6 counter).
__global__ __launch_bounds__(256, 2)
void k3_htw(const unsigned short* __restrict__ Htb, const unsigned short* __restrict__ WgT,
            unsigned short* __restrict__ h0, unsigned short* __restrict__ h1,
            unsigned short* __restrict__ h2) {
  __shared__ unsigned short shmem[17536];   // union: 4x[128][32] staging | [128][137] transpose
  unsigned short* As0 = shmem;
  unsigned short* Bs0 = shmem + 4096;
  unsigned short* As1 = shmem + 8192;
  unsigned short* Bs1 = shmem + 12288;
  const int tid = threadIdx.x;
  const int t = xcd_chunk(blockIdx.x, 144);       // 1152 blocks
  const int ch = t / 384;
  const int rc = t % 384;
  const int row0 = (rc / 6) * 128, col0 = (rc % 6) * 128;
  const unsigned short* Bt = WgT + (size_t)ch * TD * TD;
  unsigned short* H = (ch == 0) ? h0 : (ch == 1) ? h1 : h2;
  const int w = tid >> 6, lane = tid & 63;
  const int wy = w >> 1, wx = w & 1, l16 = lane & 15, quad = lane >> 4;
  floatx4 acc[4][4];
#pragma unroll
  for (int i = 0; i < 4; i++)
#pragma unroll
    for (int j = 0; j < 4; j++)
#pragma unroll
      for (int r = 0; r < 4; r++) acc[i][j][r] = 0.f;

  for (int k0 = 0; k0 < TD; k0 += 64) {
    stage_gll(Htb, TD, row0, k0, w, lane, As0);
    stage_gll(Bt, TD, col0, k0, w, lane, Bs0);
    stage_gll(Htb, TD, row0, k0 + 32, w, lane, As1);
    stage_gll(Bt, TD, col0, k0 + 32, w, lane, Bs1);
    __syncthreads();
    mfma_step_lin(As0, Bs0, wy, wx, l16, quad, acc);
    mfma_step_lin(As1, Bs1, wy, wx, l16, quad, acc);
    __syncthreads();
  }
  // transpose epilogue: acc -> lds (bf16, stride 137) -> coalesced [d][s] store
  unsigned short* lds_t = shmem;
#pragma unroll
  for (int i = 0; i < 4; i++)
#pragma unroll
    for (int j = 0; j < 4; j++)
#pragma unroll
      for (int r = 0; r < 4; r++)
        lds_t[(wy * 64 + i * 16 + quad * 4 + r) * 137 + wx * 64 + j * 16 + l16] =
            f2bf(acc[i][j][r]);
  __syncthreads();
  const int b = row0 >> 9, s0 = row0 & 511;
#pragma unroll
  for (int it = 0; it < 8; it++) {
    const int idx = tid + it * 256;
    const int d_i = idx >> 4, chunk = idx & 15;
    unsigned v[4];
#pragma unroll
    for (int e = 0; e < 4; e++) {
      const unsigned short lo = lds_t[(chunk * 8 + 2 * e) * 137 + d_i];
      const unsigned short hi = lds_t[(chunk * 8 + 2 * e + 1) * 137 + d_i];
      v[e] = (unsigned)lo | ((unsigned)hi << 16);
    }
    *(uint4*)&H[((size_t)(b * TD + col0 + d_i)) * TS + s0 + chunk * 8] =
        make_uint4(v[0], v[1], v[2], v[3]);
  }
}

// == K4n: out = mean_ch relu(Am_ch[b] @ HtW_ch^T[b] + bg_ch) * am ============
__global__ __launch_bounds__(256, 2)
void k4_outn(const unsigned short* __restrict__ Am,
             const unsigned short* __restrict__ h0, const unsigned short* __restrict__ h1,
             const unsigned short* __restrict__ h2,
             const float* __restrict__ bg, const float* __restrict__ am,
             float* __restrict__ out) {
  __shared__ unsigned short As0[128 * 32], As1[128 * 32];
  __shared__ unsigned short Bs0[128 * 32], Bs1[128 * 32];
  const int tid = threadIdx.x;
  const int t = xcd_chunk(blockIdx.x, 48);        // 384 blocks
  const int row0 = (t / 6) * 128, col0 = (t % 6) * 128;
  const int b = row0 >> 9, q0_ = row0 & 511;
  const int w = tid >> 6, lane = tid & 63;
  const int wy = w >> 1, wx = w & 1, l16 = lane & 15, quad = lane >> 4;
  float osum[4][4][4];
#pragma unroll
  for (int i = 0; i < 4; i++)
#pragma unroll
    for (int j = 0; j < 4; j++)
#pragma unroll
      for (int r = 0; r < 4; r++) osum[i][j][r] = 0.f;

  for (int ch = 0; ch < TNCH; ch++) {
    const unsigned short* A  = Am + (size_t)(ch * TB + b) * TS * TS;
    const unsigned short* Bt = ((ch == 0) ? h0 : (ch == 1) ? h1 : h2) + (size_t)b * TD * TS;
    floatx4 acc[4][4];
#pragma unroll
    for (int i = 0; i < 4; i++)
#pragma unroll
      for (int j = 0; j < 4; j++)
#pragma unroll
        for (int r = 0; r < 4; r++) acc[i][j][r] = 0.f;

    for (int k0 = 0; k0 < TS; k0 += 64) {
      stage_gll(A, TS, q0_, k0, w, lane, As0);
      stage_gll(Bt, TS, col0, k0, w, lane, Bs0);
      stage_gll(A, TS, q0_, k0 + 32, w, lane, As1);
      stage_gll(Bt, TS, col0, k0 + 32, w, lane, Bs1);
      __syncthreads();
      mfma_step_lin(As0, Bs0, wy, wx, l16, quad, acc);
      mfma_step_lin(As1, Bs1, wy, wx, l16, quad, acc);
      __syncthreads();
    }
#pragma unroll
    for (int i = 0; i < 4; i++)
#pragma unroll
      for (int j = 0; j < 4; j++) {
        const int col = col0 + wx * 64 + j * 16 + l16;
        const float bs = bg[ch * TD + col];
#pragma unroll
        for (int r = 0; r < 4; r++)
          osum[i][j][r] += fmaxf(acc[i][j][r] + bs, 0.f);
      }
  }
#pragma unroll
  for (int i = 0; i < 4; i++)
#pragma unroll
    for (int r = 0; r < 4; r++) {
      const int row = row0 + wy * 64 + i * 16 + quad * 4 + r;
      const float amr = am[row] * (1.f / 3.f);
#pragma unroll
      for (int j = 0; j < 4; j++) {
        const int col = col0 + wx * 64 + j * 16 + l16;
        out[(size_t)row * TD + col] = osum[i][j][r] * amr;
      }
    }
}

extern "C" void kernel_launch(void* const* d_in, const int* in_sizes, int n_in,
                              void* d_out, int out_size, void* d_ws, size_t ws_size,
                              hipStream_t stream) {
  const float* Ht    = (const float*)d_in[0];
  const float* Ml    = (const float*)d_in[1];
  const float* am    = (const float*)d_in[2];
  const float* W_qk  = (const float*)d_in[3];
  const float* b_qk  = (const float*)d_in[4];
  const float* W_gat = (const float*)d_in[5];
  const float* b_gat = (const float*)d_in[6];
  float* out = (float*)d_out;

  // ws layout (ushorts):
  //   Q / HtW0  [0,        SEG)      k1 writes Q; k3n overwrites as HtW0^T
  //   Kw / HtW1 [SEG,     2SEG)      k1 writes K; k3n overwrites as HtW1^T
  //   Htb       [2SEG,    3SEG)      bf16(Ht) — read by k1, k3n
  //   HtW2      [3SEG,    4SEG)      k3n output (old HtbT slot, now unused)
  //   WqkT      [4SEG, ...)          [1536][768]
  //   WgT       after WqkT           [3][768][768]
  //   Am        after WgT            [3][16][512][512]
  unsigned short* base = (unsigned short*)d_ws;
  const size_t SEG = (size_t)TB * TS * TD;            // 6291456
  unsigned short* Q    = base;
  unsigned short* Kw   = base + SEG;
  unsigned short* Htb  = base + 2 * SEG;
  unsigned short* HtW2 = base + 3 * SEG;
  unsigned short* WqkT = base + 4 * SEG;
  unsigned short* WgT  = WqkT + (size_t)TD * 2 * TD;
  unsigned short* Am   = WgT + (size_t)TNCH * TD * TD;
  unsigned short* HtW0 = Q;      // dead after k2
  unsigned short* HtW1 = Kw;     // dead after k2

  // prep
  pconv <<<dim3(3072), 256, 0, stream>>>(Ht, Htb);
  ptrans<<<dim3(48, 24, 1), 256, 0, stream>>>(W_qk, WqkT, TD, 2 * TD);
  ptrans<<<dim3(24, 24, 3), 256, 0, stream>>>(W_gat, WgT, TD, TD);

  k1_qk  <<<dim3(768),  256, 0, stream>>>(Htb, WqkT, b_qk, Q, Kw);
  k2_attn<<<dim3(512),  256, 0, stream>>>(Q, Kw, Ml, am, Am);
  k3_htw <<<dim3(1152), 256, 0, stream>>>(Htb, WgT, HtW0, HtW1, HtW2);
  k4_outn<<<dim3(384),  256, 0, stream>>>(Am, HtW0, HtW1, HtW2, b_gat, am, out);
}

// Round 17
// 327.953 us; speedup vs baseline: 1.3125x; 1.0101x over previous
//
#include <hip/hip_runtime.h>
#include <math.h>

typedef __attribute__((ext_vector_type(8))) short short8;
typedef __attribute__((ext_vector_type(4))) float floatx4;

#define TB 16
#define TS 512
#define TD 768
#define TH 12
#define TDH 64
#define TNCH 3

#define SCALE 0.03608439182435161f  // 1/sqrt(768)

__device__ __forceinline__ unsigned short f2bf(float f) {
  unsigned u = __float_as_uint(f);
  u += 0x7fffu + ((u >> 16) & 1u);   // round-to-nearest-even
  return (unsigned short)(u >> 16);
}
__device__ __forceinline__ unsigned f2bf2(float lo, float hi) {
  return (unsigned)f2bf(lo) | ((unsigned)f2bf(hi) << 16);
}

union U4 { uint4 u; short8 s; };

// ===== prep_all: pconv(Ht) + ptrans(W_qk) + ptrans(W_gat) in ONE launch =====
// block roles: [0,3072) pconv | [3072,4224) W_qk transpose | [4224,5952) W_gat.
__global__ __launch_bounds__(256)
void prep_all(const float* __restrict__ Ht, const float* __restrict__ Wqk,
              const float* __restrict__ Wg, unsigned short* __restrict__ Htb,
              unsigned short* __restrict__ WqkT, unsigned short* __restrict__ WgT) {
  __shared__ float ts[32][33];
  const int bid = blockIdx.x;
  if (bid < 3072) {
    const int i = (bid * 256 + threadIdx.x) * 8;
    const float4 a = *(const float4*)&Ht[i];
    const float4 b = *(const float4*)&Ht[i + 4];
    uint4 o;
    o.x = f2bf2(a.x, a.y); o.y = f2bf2(a.z, a.w);
    o.z = f2bf2(b.x, b.y); o.w = f2bf2(b.z, b.w);
    *(uint4*)&Htb[i] = o;
    return;
  }
  const float* src; unsigned short* dst; int R, C, bx, by, z;
  if (bid < 4224) {
    const int i = bid - 3072;
    bx = i % 48; by = i / 48; z = 0;
    src = Wqk; dst = WqkT; R = TD; C = 2 * TD;
  } else {
    const int i = bid - 4224;
    bx = i % 24; by = (i / 24) % 24; z = i / 576;
    src = Wg; dst = WgT; R = TD; C = TD;
  }
  const size_t zoff = (size_t)z * R * C;
  src += zoff; dst += zoff;
  const int c0 = bx * 32, r0 = by * 32;
  const int x = threadIdx.x & 31, y = threadIdx.x >> 5;
#pragma unroll
  for (int i = 0; i < 4; i++)
    ts[y + 8 * i][x] = src[(size_t)(r0 + y + 8 * i) * C + c0 + x];
  __syncthreads();
#pragma unroll
  for (int i = 0; i < 4; i++)
    dst[(size_t)(c0 + y + 8 * i) * R + r0 + x] = f2bf(ts[x][y + 8 * i]);
}

// ---- GEMM staging: async global->LDS, width 16, linear [128][32] (m97) ----
__device__ __forceinline__ void stage_gll(const unsigned short* __restrict__ S, int ld,
                                          int row0, int k0, int w, int lane,
                                          unsigned short* D) {
  const int rsub = lane >> 2, c = lane & 3;
#pragma unroll
  for (int i = 0; i < 2; i++) {
    const int r = w * 32 + i * 16;
    const unsigned short* g = &S[(size_t)(row0 + r + rsub) * ld + k0 + c * 8];
    unsigned short* d = &D[r * 32];
    __builtin_amdgcn_global_load_lds(
        (const __attribute__((address_space(1))) unsigned int*)(const void*)g,
        (__attribute__((address_space(3))) unsigned int*)(void*)d,
        16, 0, 0);
  }
}

// 96-row B tile: 4 waves cover rows 0..63, waves 0..1 cover rows 64..95
__device__ __forceinline__ void stage_gll96(const unsigned short* __restrict__ S, int ld,
                                            int row0, int k0, int w, int lane,
                                            unsigned short* D) {
  const int rsub = lane >> 2, c = lane & 3;
  {
    const int r = w * 16;
    const unsigned short* g = &S[(size_t)(row0 + r + rsub) * ld + k0 + c * 8];
    __builtin_amdgcn_global_load_lds(
        (const __attribute__((address_space(1))) unsigned int*)(const void*)g,
        (__attribute__((address_space(3))) unsigned int*)(void*)&D[r * 32],
        16, 0, 0);
  }
  if (w < 2) {
    const int r = 64 + w * 16;
    const unsigned short* g = &S[(size_t)(row0 + r + rsub) * ld + k0 + c * 8];
    __builtin_amdgcn_global_load_lds(
        (const __attribute__((address_space(1))) unsigned int*)(const void*)g,
        (__attribute__((address_space(3))) unsigned int*)(void*)&D[r * 32],
        16, 0, 0);
  }
}

__device__ __forceinline__ void mfma_step_lin(const unsigned short* As, const unsigned short* Bs,
                                              int wy, int wx, int l16, int quad,
                                              floatx4 acc[4][4]) {
  short8 af[4], bfr[4];
#pragma unroll
  for (int i = 0; i < 4; i++) {
    U4 t; t.u = *(const uint4*)&As[(wy * 64 + i * 16 + l16) * 32 + quad * 8];
    af[i] = t.s;
  }
#pragma unroll
  for (int j = 0; j < 4; j++) {
    U4 t; t.u = *(const uint4*)&Bs[(wx * 64 + j * 16 + l16) * 32 + quad * 8];
    bfr[j] = t.s;
  }
#pragma unroll
  for (int i = 0; i < 4; i++)
#pragma unroll
    for (int j = 0; j < 4; j++)
      acc[i][j] = __builtin_amdgcn_mfma_f32_16x16x32_bf16(af[i], bfr[j], acc[i][j], 0, 0, 0);
}

// == XCD-aware chunked swizzle (T1, verified: -29 us) ========================
__device__ __forceinline__ int xcd_chunk(int bid, int cpx) {
  return (bid & 7) * cpx + (bid >> 3);
}

// ===== K1: qk = Htb @ WqkT^T + b_qk; paired k-steps, swizzled ===============
__global__ __launch_bounds__(256, 2)
void k1_qk(const unsigned short* __restrict__ Htb, const unsigned short* __restrict__ WqkT,
           const float* __restrict__ bias, unsigned short* __restrict__ Q,
           unsigned short* __restrict__ Ko) {
  __shared__ unsigned short As0[128 * 32], As1[128 * 32];
  __shared__ unsigned short Bs0[128 * 32], Bs1[128 * 32];
  const int tid = threadIdx.x;
  const int t = xcd_chunk(blockIdx.x, 96);
  const int row0 = (t / 12) * 128, col0 = (t % 12) * 128;
  const int w = tid >> 6, lane = tid & 63;
  const int wy = w >> 1, wx = w & 1, l16 = lane & 15, quad = lane >> 4;
  floatx4 acc[4][4];
#pragma unroll
  for (int i = 0; i < 4; i++)
#pragma unroll
    for (int j = 0; j < 4; j++)
#pragma unroll
      for (int r = 0; r < 4; r++) acc[i][j][r] = 0.f;

  for (int k0 = 0; k0 < TD; k0 += 64) {
    stage_gll(Htb, TD, row0, k0, w, lane, As0);
    stage_gll(WqkT, TD, col0, k0, w, lane, Bs0);
    stage_gll(Htb, TD, row0, k0 + 32, w, lane, As1);
    stage_gll(WqkT, TD, col0, k0 + 32, w, lane, Bs1);
    __syncthreads();
    mfma_step_lin(As0, Bs0, wy, wx, l16, quad, acc);
    mfma_step_lin(As1, Bs1, wy, wx, l16, quad, acc);
    __syncthreads();
  }
#pragma unroll
  for (int i = 0; i < 4; i++)
#pragma unroll
    for (int j = 0; j < 4; j++) {
      const int col = col0 + wx * 64 + j * 16 + l16;
      const float bs = bias[col];
#pragma unroll
      for (int r = 0; r < 4; r++) {
        const int row = row0 + wy * 64 + i * 16 + quad * 4 + r;
        const float v = acc[i][j][r] + bs;
        if (col < TD) Q[(size_t)row * TD + col] = f2bf(v);
        else          Ko[(size_t)row * TD + (col - TD)] = f2bf(v);
      }
    }
}

// ==== K2: MFMA scores; no-max-sub two-pass softmax (R9 exact, 128 us) =======
#define OB_S 520
__global__ __launch_bounds__(256, 2)
void k2_attn(const unsigned short* __restrict__ Q, const unsigned short* __restrict__ Kb,
             const float* __restrict__ Ml, const float* __restrict__ am,
             unsigned short* __restrict__ Am) {
  __shared__ float4 ldsf4[1040];
  const int i0 = blockIdx.x;
  const int xcd = i0 & 7, jj = i0 >> 3;
  const int b = xcd + 8 * (jj & 1);
  const int q0 = (jj >> 1) * 16;
  const int tid = threadIdx.x;
  const int w = tid >> 6, lane = tid & 63;
  const int l16 = lane & 15, quad = lane >> 4;
  const int kbase = w * 128;

  const float* amb = am + b * TS;
  float amq[4], amk[8], maskv[8];
#pragma unroll
  for (int r = 0; r < 4; r++) amq[r] = amb[q0 + quad * 4 + r];
#pragma unroll
  for (int kt = 0; kt < 8; kt++) {
    amk[kt] = amb[kbase + kt * 16 + l16];
    maskv[kt] = (1.f - amk[kt]) * (-1e9f);
  }

  unsigned Mpk[TNCH][4][4];
#pragma unroll
  for (int i = 0; i < TNCH; i++)
#pragma unroll
    for (int r = 0; r < 4; r++) {
      const float* Mrow = Ml + ((size_t)((b * TNCH + i) * TS + q0 + quad * 4 + r)) * TS;
#pragma unroll
      for (int kt2 = 0; kt2 < 4; kt2++) {
        const int ke = kbase + kt2 * 32 + l16;
        const float me = Mrow[ke] * amk[kt2 * 2] * amq[r];
        const float mo = Mrow[ke + 16] * amk[kt2 * 2 + 1] * amq[r];
        Mpk[i][r][kt2] = f2bf2(me, mo);
      }
    }

  const unsigned short* qbase = Q + ((size_t)(b * TS + q0 + l16)) * TD + quad * 8;
  const unsigned short* kb0   = Kb + ((size_t)(b * TS + kbase + l16)) * TD + quad * 8;

  for (int h = 0; h < TH; h++) {
    floatx4 sacc[8];
#pragma unroll
    for (int kt = 0; kt < 8; kt++)
#pragma unroll
      for (int r = 0; r < 4; r++) sacc[kt][r] = 0.f;
#pragma unroll
    for (int dk = 0; dk < 2; dk++) {
      U4 a; a.u = *(const uint4*)(qbase + h * TDH + dk * 32);
#pragma unroll
      for (int kt = 0; kt < 8; kt++) {
        U4 bb; bb.u = *(const uint4*)(kb0 + (size_t)kt * 16 * TD + h * TDH + dk * 32);
        sacc[kt] = __builtin_amdgcn_mfma_f32_16x16x32_bf16(a.s, bb.s, sacc[kt], 0, 0, 0);
      }
    }
    float e[8][4];
    float Zp[4] = {0.f, 0.f, 0.f, 0.f};
#pragma unroll
    for (int kt = 0; kt < 8; kt++)
#pragma unroll
      for (int r = 0; r < 4; r++) {
        const float v = __expf(sacc[kt][r] * SCALE + maskv[kt]);
        e[kt][r] = v;
        Zp[r] += v;
      }
    float dmp[TNCH][4];
#pragma unroll
    for (int i = 0; i < TNCH; i++)
#pragma unroll
      for (int r = 0; r < 4; r++) {
        float d = 0.f;
#pragma unroll
        for (int kt2 = 0; kt2 < 4; kt2++) {
          const unsigned u = Mpk[i][r][kt2];
          d += __uint_as_float(u << 16) * e[kt2 * 2][r];
          d += __uint_as_float(u & 0xffff0000u) * e[kt2 * 2 + 1][r];
        }
        dmp[i][r] = d;
      }
#pragma unroll
    for (int r = 0; r < 4; r++) {
#pragma unroll
      for (int off = 1; off < 16; off <<= 1) {
        Zp[r] += __shfl_xor(Zp[r], off);
        dmp[0][r] += __shfl_xor(dmp[0][r], off);
        dmp[1][r] += __shfl_xor(dmp[1][r], off);
        dmp[2][r] += __shfl_xor(dmp[2][r], off);
      }
    }
    if (l16 == 0) {
#pragma unroll
      for (int r = 0; r < 4; r++)
        ldsf4[(h * 16 + quad * 4 + r) * 4 + w] =
            make_float4(Zp[r], dmp[0][r], dmp[1][r], dmp[2][r]);
    }
  }
  __syncthreads();

  if (tid < TH * 16) {
    const int h = tid >> 4, q = tid & 15;
    const int base = (h * 16 + q) * 4;
    const float4 p0 = ldsf4[base + 0];
    const float4 p1 = ldsf4[base + 1];
    const float4 p2 = ldsf4[base + 2];
    const float4 p3 = ldsf4[base + 3];
    const float Z  = p0.x + p1.x + p2.x + p3.x;
    const float d0 = p0.y + p1.y + p2.y + p3.y;
    const float d1 = p0.z + p1.z + p2.z + p3.z;
    const float d2 = p0.w + p1.w + p2.w + p3.w;
    const float ez = 1e-10f * Z + 1e-30f;
    ldsf4[768 + h * 16 + q] =
        make_float4(1.f / (d0 + ez), 1.f / (d1 + ez), 1.f / (d2 + ez), 0.f);
  }
  __syncthreads();

  float acc[TNCH][8][4];
#pragma unroll
  for (int i = 0; i < TNCH; i++)
#pragma unroll
    for (int kt = 0; kt < 8; kt++)
#pragma unroll
      for (int r = 0; r < 4; r++) acc[i][kt][r] = 0.f;

  for (int h = 0; h < TH; h++) {
    floatx4 sacc[8];
#pragma unroll
    for (int kt = 0; kt < 8; kt++)
#pragma unroll
      for (int r = 0; r < 4; r++) sacc[kt][r] = 0.f;
#pragma unroll
    for (int dk = 0; dk < 2; dk++) {
      U4 a; a.u = *(const uint4*)(qbase + h * TDH + dk * 32);
#pragma unroll
      for (int kt = 0; kt < 8; kt++) {
        U4 bb; bb.u = *(const uint4*)(kb0 + (size_t)kt * 16 * TD + h * TDH + dk * 32);
        sacc[kt] = __builtin_amdgcn_mfma_f32_16x16x32_bf16(a.s, bb.s, sacc[kt], 0, 0, 0);
      }
    }
    float4 wv[4];
#pragma unroll
    for (int r = 0; r < 4; r++) wv[r] = ldsf4[768 + h * 16 + quad * 4 + r];
#pragma unroll
    for (int kt = 0; kt < 8; kt++)
#pragma unroll
      for (int r = 0; r < 4; r++) {
        const float v = __expf(sacc[kt][r] * SCALE + maskv[kt]);
        acc[0][kt][r] += v * wv[r].x;
        acc[1][kt][r] += v * wv[r].y;
        acc[2][kt][r] += v * wv[r].z;
      }
  }
  __syncthreads();

  unsigned short* obuf = (unsigned short*)ldsf4;
  const float inv_h = 1.f / (float)TH;
  for (int i = 0; i < TNCH; i++) {
#pragma unroll
    for (int r = 0; r < 4; r++) {
      const int q = q0 + quad * 4 + r;
      const float* Mrow = Ml + ((size_t)((b * TNCH + i) * TS + q)) * TS;
#pragma unroll
      for (int kt = 0; kt < 8; kt++) {
        const int k = kbase + kt * 16 + l16;
        const float mv = Mrow[k] * amk[kt] * amq[r];
        obuf[(quad * 4 + r) * OB_S + k] = f2bf(mv * acc[i][kt][r] * inv_h);
      }
    }
    __syncthreads();
#pragma unroll
    for (int it = 0; it < 4; it++) {
      const int idx = tid + it * 256;
      const int row = idx >> 6, c16 = idx & 63;
      const uint4 v = *(const uint4*)&obuf[row * OB_S + c16 * 8];
      *(uint4*)&Am[((size_t)((i * TB + b) * TS + q0 + row)) * TS + c16 * 8] = v;
    }
    __syncthreads();
  }
}

// ===== K3n: HtW_ch = Htb @ WgT_ch^T, stored TRANSPOSED per (ch,b): [768][512]
__global__ __launch_bounds__(256, 2)
void k3_htw(const unsigned short* __restrict__ Htb, const unsigned short* __restrict__ WgT,
            unsigned short* __restrict__ h0, unsigned short* __restrict__ h1,
            unsigned short* __restrict__ h2) {
  __shared__ unsigned short shmem[17536];   // union: 4x[128][32] staging | [128][137]
  unsigned short* As0 = shmem;
  unsigned short* Bs0 = shmem + 4096;
  unsigned short* As1 = shmem + 8192;
  unsigned short* Bs1 = shmem + 12288;
  const int tid = threadIdx.x;
  const int t = xcd_chunk(blockIdx.x, 144);       // 1152 blocks
  const int ch = t / 384;
  const int rc = t % 384;
  const int row0 = (rc / 6) * 128, col0 = (rc % 6) * 128;
  const unsigned short* Bt = WgT + (size_t)ch * TD * TD;
  unsigned short* H = (ch == 0) ? h0 : (ch == 1) ? h1 : h2;
  const int w = tid >> 6, lane = tid & 63;
  const int wy = w >> 1, wx = w & 1, l16 = lane & 15, quad = lane >> 4;
  floatx4 acc[4][4];
#pragma unroll
  for (int i = 0; i < 4; i++)
#pragma unroll
    for (int j = 0; j < 4; j++)
#pragma unroll
      for (int r = 0; r < 4; r++) acc[i][j][r] = 0.f;

  for (int k0 = 0; k0 < TD; k0 += 64) {
    stage_gll(Htb, TD, row0, k0, w, lane, As0);
    stage_gll(Bt, TD, col0, k0, w, lane, Bs0);
    stage_gll(Htb, TD, row0, k0 + 32, w, lane, As1);
    stage_gll(Bt, TD, col0, k0 + 32, w, lane, Bs1);
    __syncthreads();
    mfma_step_lin(As0, Bs0, wy, wx, l16, quad, acc);
    mfma_step_lin(As1, Bs1, wy, wx, l16, quad, acc);
    __syncthreads();
  }
  unsigned short* lds_t = shmem;
#pragma unroll
  for (int i = 0; i < 4; i++)
#pragma unroll
    for (int j = 0; j < 4; j++)
#pragma unroll
      for (int r = 0; r < 4; r++)
        lds_t[(wy * 64 + i * 16 + quad * 4 + r) * 137 + wx * 64 + j * 16 + l16] =
            f2bf(acc[i][j][r]);
  __syncthreads();
  const int b = row0 >> 9, s0 = row0 & 511;
#pragma unroll
  for (int it = 0; it < 8; it++) {
    const int idx = tid + it * 256;
    const int d_i = idx >> 4, chunk = idx & 15;
    unsigned v[4];
#pragma unroll
    for (int e = 0; e < 4; e++) {
      const unsigned short lo = lds_t[(chunk * 8 + 2 * e) * 137 + d_i];
      const unsigned short hi = lds_t[(chunk * 8 + 2 * e + 1) * 137 + d_i];
      v[e] = (unsigned)lo | ((unsigned)hi << 16);
    }
    *(uint4*)&H[((size_t)(b * TD + col0 + d_i)) * TS + s0 + chunk * 8] =
        make_uint4(v[0], v[1], v[2], v[3]);
  }
}

// == K4n: out = mean_ch relu(Am_ch[b] @ HtW_ch^T[b] + bg_ch) * am ============
// R20: 128x96 tiles -> grid 512 = exactly 2 blocks/CU (was 384 = 1.5, tail).
__global__ __launch_bounds__(256, 2)
void k4_outn(const unsigned short* __restrict__ Am,
             const unsigned short* __restrict__ h0, const unsigned short* __restrict__ h1,
             const unsigned short* __restrict__ h2,
             const float* __restrict__ bg, const float* __restrict__ am,
             float* __restrict__ out) {
  __shared__ unsigned short As0[128 * 32], As1[128 * 32];
  __shared__ unsigned short Bs0[96 * 32], Bs1[96 * 32];
  const int tid = threadIdx.x;
  const int t = xcd_chunk(blockIdx.x, 64);        // 512 blocks
  const int row0 = (t >> 3) * 128, col0 = (t & 7) * 96;
  const int b = row0 >> 9, q0_ = row0 & 511;
  const int w = tid >> 6, lane = tid & 63;
  const int wy = w >> 1, wx = w & 1, l16 = lane & 15, quad = lane >> 4;
  float osum[4][3][4];
#pragma unroll
  for (int i = 0; i < 4; i++)
#pragma unroll
    for (int j = 0; j < 3; j++)
#pragma unroll
      for (int r = 0; r < 4; r++) osum[i][j][r] = 0.f;

  for (int ch = 0; ch < TNCH; ch++) {
    const unsigned short* A  = Am + (size_t)(ch * TB + b) * TS * TS;
    const unsigned short* Bt = ((ch == 0) ? h0 : (ch == 1) ? h1 : h2) + (size_t)b * TD * TS;
    floatx4 acc[4][3];
#pragma unroll
    for (int i = 0; i < 4; i++)
#pragma unroll
      for (int j = 0; j < 3; j++)
#pragma unroll
        for (int r = 0; r < 4; r++) acc[i][j][r] = 0.f;

    for (int k0 = 0; k0 < TS; k0 += 64) {
      stage_gll(A, TS, q0_, k0, w, lane, As0);
      stage_gll96(Bt, TS, col0, k0, w, lane, Bs0);
      stage_gll(A, TS, q0_, k0 + 32, w, lane, As1);
      stage_gll96(Bt, TS, col0, k0 + 32, w, lane, Bs1);
      __syncthreads();
      {
        short8 af[4], bfr[3];
#pragma unroll
        for (int i = 0; i < 4; i++) {
          U4 tt; tt.u = *(const uint4*)&As0[(wy * 64 + i * 16 + l16) * 32 + quad * 8];
          af[i] = tt.s;
        }
#pragma unroll
        for (int j = 0; j < 3; j++) {
          U4 tt; tt.u = *(const uint4*)&Bs0[(wx * 48 + j * 16 + l16) * 32 + quad * 8];
          bfr[j] = tt.s;
        }
#pragma unroll
        for (int i = 0; i < 4; i++)
#pragma unroll
          for (int j = 0; j < 3; j++)
            acc[i][j] = __builtin_amdgcn_mfma_f32_16x16x32_bf16(af[i], bfr[j], acc[i][j], 0, 0, 0);
      }
      {
        short8 af[4], bfr[3];
#pragma unroll
        for (int i = 0; i < 4; i++) {
          U4 tt; tt.u = *(const uint4*)&As1[(wy * 64 + i * 16 + l16) * 32 + quad * 8];
          af[i] = tt.s;
        }
#pragma unroll
        for (int j = 0; j < 3; j++) {
          U4 tt; tt.u = *(const uint4*)&Bs1[(wx * 48 + j * 16 + l16) * 32 + quad * 8];
          bfr[j] = tt.s;
        }
#pragma unroll
        for (int i = 0; i < 4; i++)
#pragma unroll
          for (int j = 0; j < 3; j++)
            acc[i][j] = __builtin_amdgcn_mfma_f32_16x16x32_bf16(af[i], bfr[j], acc[i][j], 0, 0, 0);
      }
      __syncthreads();
    }
#pragma unroll
    for (int i = 0; i < 4; i++)
#pragma unroll
      for (int j = 0; j < 3; j++) {
        const int col = col0 + wx * 48 + j * 16 + l16;
        const float bs = bg[ch * TD + col];
#pragma unroll
        for (int r = 0; r < 4; r++)
          osum[i][j][r] += fmaxf(acc[i][j][r] + bs, 0.f);
      }
  }
#pragma unroll
  for (int i = 0; i < 4; i++)
#pragma unroll
    for (int r = 0; r < 4; r++) {
      const int row = row0 + wy * 64 + i * 16 + quad * 4 + r;
      const float amr = am[row] * (1.f / 3.f);
#pragma unroll
      for (int j = 0; j < 3; j++) {
        const int col = col0 + wx * 48 + j * 16 + l16;
        out[(size_t)row * TD + col] = osum[i][j][r] * amr;
      }
    }
}

extern "C" void kernel_launch(void* const* d_in, const int* in_sizes, int n_in,
                              void* d_out, int out_size, void* d_ws, size_t ws_size,
                              hipStream_t stream) {
  const float* Ht    = (const float*)d_in[0];
  const float* Ml    = (const float*)d_in[1];
  const float* am    = (const float*)d_in[2];
  const float* W_qk  = (const float*)d_in[3];
  const float* b_qk  = (const float*)d_in[4];
  const float* W_gat = (const float*)d_in[5];
  const float* b_gat = (const float*)d_in[6];
  float* out = (float*)d_out;

  // ws layout (ushorts):
  //   Q / HtW0  [0,        SEG)      k1 writes Q; k3n overwrites as HtW0^T
  //   Kw / HtW1 [SEG,     2SEG)      k1 writes K; k3n overwrites as HtW1^T
  //   Htb       [2SEG,    3SEG)      bf16(Ht) — read by k1, k3n
  //   HtW2      [3SEG,    4SEG)
  //   WqkT      [4SEG, ...)          [1536][768]
  //   WgT       after WqkT           [3][768][768]
  //   Am        after WgT            [3][16][512][512]
  unsigned short* base = (unsigned short*)d_ws;
  const size_t SEG = (size_t)TB * TS * TD;            // 6291456
  unsigned short* Q    = base;
  unsigned short* Kw   = base + SEG;
  unsigned short* Htb  = base + 2 * SEG;
  unsigned short* HtW2 = base + 3 * SEG;
  unsigned short* WqkT = base + 4 * SEG;
  unsigned short* WgT  = WqkT + (size_t)TD * 2 * TD;
  unsigned short* Am   = WgT + (size_t)TNCH * TD * TD;
  unsigned short* HtW0 = Q;      // dead after k2
  unsigned short* HtW1 = Kw;     // dead after k2

  prep_all<<<dim3(5952), 256, 0, stream>>>(Ht, W_qk, W_gat, Htb, WqkT, WgT);

  k1_qk  <<<dim3(768),  256, 0, stream>>>(Htb, WqkT, b_qk, Q, Kw);
  k2_attn<<<dim3(512),  256, 0, stream>>>(Q, Kw, Ml, am, Am);
  k3_htw <<<dim3(1152), 256, 0, stream>>>(Htb, WgT, HtW0, HtW1, HtW2);
  k4_outn<<<dim3(512),  256, 0, stream>>>(Am, HtW0, HtW1, HtW2, b_gat, am, out);
}

// Round 18
// 325.152 us; speedup vs baseline: 1.3238x; 1.0086x over previous
//
#include <hip/hip_runtime.h>
#include <math.h>

typedef __attribute__((ext_vector_type(8))) short short8;
typedef __attribute__((ext_vector_type(4))) float floatx4;

#define TB 16
#define TS 512
#define TD 768
#define TH 12
#define TDH 64
#define TNCH 3

#define SCALE 0.03608439182435161f  // 1/sqrt(768)

__device__ __forceinline__ unsigned short f2bf(float f) {
  unsigned u = __float_as_uint(f);
  u += 0x7fffu + ((u >> 16) & 1u);   // round-to-nearest-even
  return (unsigned short)(u >> 16);
}
__device__ __forceinline__ unsigned f2bf2(float lo, float hi) {
  return (unsigned)f2bf(lo) | ((unsigned)f2bf(hi) << 16);
}

union U4 { uint4 u; short8 s; };

// ===== prep_all: pconv(Ht) + ptrans(W_qk) + ptrans(W_gat) in ONE launch =====
__global__ __launch_bounds__(256)
void prep_all(const float* __restrict__ Ht, const float* __restrict__ Wqk,
              const float* __restrict__ Wg, unsigned short* __restrict__ Htb,
              unsigned short* __restrict__ WqkT, unsigned short* __restrict__ WgT) {
  __shared__ float ts[32][33];
  const int bid = blockIdx.x;
  if (bid < 3072) {
    const int i = (bid * 256 + threadIdx.x) * 8;
    const float4 a = *(const float4*)&Ht[i];
    const float4 b = *(const float4*)&Ht[i + 4];
    uint4 o;
    o.x = f2bf2(a.x, a.y); o.y = f2bf2(a.z, a.w);
    o.z = f2bf2(b.x, b.y); o.w = f2bf2(b.z, b.w);
    *(uint4*)&Htb[i] = o;
    return;
  }
  const float* src; unsigned short* dst; int R, C, bx, by, z;
  if (bid < 4224) {
    const int i = bid - 3072;
    bx = i % 48; by = i / 48; z = 0;
    src = Wqk; dst = WqkT; R = TD; C = 2 * TD;
  } else {
    const int i = bid - 4224;
    bx = i % 24; by = (i / 24) % 24; z = i / 576;
    src = Wg; dst = WgT; R = TD; C = TD;
  }
  const size_t zoff = (size_t)z * R * C;
  src += zoff; dst += zoff;
  const int c0 = bx * 32, r0 = by * 32;
  const int x = threadIdx.x & 31, y = threadIdx.x >> 5;
#pragma unroll
  for (int i = 0; i < 4; i++)
    ts[y + 8 * i][x] = src[(size_t)(r0 + y + 8 * i) * C + c0 + x];
  __syncthreads();
#pragma unroll
  for (int i = 0; i < 4; i++)
    dst[(size_t)(c0 + y + 8 * i) * R + r0 + x] = f2bf(ts[x][y + 8 * i]);
}

// ---- GEMM staging: async global->LDS, width 16, linear [128][32] (m97) ----
__device__ __forceinline__ void stage_gll(const unsigned short* __restrict__ S, int ld,
                                          int row0, int k0, int w, int lane,
                                          unsigned short* D) {
  const int rsub = lane >> 2, c = lane & 3;
#pragma unroll
  for (int i = 0; i < 2; i++) {
    const int r = w * 32 + i * 16;
    const unsigned short* g = &S[(size_t)(row0 + r + rsub) * ld + k0 + c * 8];
    unsigned short* d = &D[r * 32];
    __builtin_amdgcn_global_load_lds(
        (const __attribute__((address_space(1))) unsigned int*)(const void*)g,
        (__attribute__((address_space(3))) unsigned int*)(void*)d,
        16, 0, 0);
  }
}

// 96-row B tile: 4 waves cover rows 0..63, waves 0..1 cover rows 64..95
__device__ __forceinline__ void stage_gll96(const unsigned short* __restrict__ S, int ld,
                                            int row0, int k0, int w, int lane,
                                            unsigned short* D) {
  const int rsub = lane >> 2, c = lane & 3;
  {
    const int r = w * 16;
    const unsigned short* g = &S[(size_t)(row0 + r + rsub) * ld + k0 + c * 8];
    __builtin_amdgcn_global_load_lds(
        (const __attribute__((address_space(1))) unsigned int*)(const void*)g,
        (__attribute__((address_space(3))) unsigned int*)(void*)&D[r * 32],
        16, 0, 0);
  }
  if (w < 2) {
    const int r = 64 + w * 16;
    const unsigned short* g = &S[(size_t)(row0 + r + rsub) * ld + k0 + c * 8];
    __builtin_amdgcn_global_load_lds(
        (const __attribute__((address_space(1))) unsigned int*)(const void*)g,
        (__attribute__((address_space(3))) unsigned int*)(void*)&D[r * 32],
        16, 0, 0);
  }
}

__device__ __forceinline__ void mfma_step_lin(const unsigned short* As, const unsigned short* Bs,
                                              int wy, int wx, int l16, int quad,
                                              floatx4 acc[4][4]) {
  short8 af[4], bfr[4];
#pragma unroll
  for (int i = 0; i < 4; i++) {
    U4 t; t.u = *(const uint4*)&As[(wy * 64 + i * 16 + l16) * 32 + quad * 8];
    af[i] = t.s;
  }
#pragma unroll
  for (int j = 0; j < 4; j++) {
    U4 t; t.u = *(const uint4*)&Bs[(wx * 64 + j * 16 + l16) * 32 + quad * 8];
    bfr[j] = t.s;
  }
#pragma unroll
  for (int i = 0; i < 4; i++)
#pragma unroll
    for (int j = 0; j < 4; j++)
      acc[i][j] = __builtin_amdgcn_mfma_f32_16x16x32_bf16(af[i], bfr[j], acc[i][j], 0, 0, 0);
}

// == XCD-aware chunked swizzle (T1, verified: -29 us) ========================
__device__ __forceinline__ int xcd_chunk(int bid, int cpx) {
  return (bid & 7) * cpx + (bid >> 3);
}

// ===== K1: qk = Htb @ WqkT^T + b_qk; paired k-steps, swizzled ===============
__global__ __launch_bounds__(256, 2)
void k1_qk(const unsigned short* __restrict__ Htb, const unsigned short* __restrict__ WqkT,
           const float* __restrict__ bias, unsigned short* __restrict__ Q,
           unsigned short* __restrict__ Ko) {
  __shared__ unsigned short As0[128 * 32], As1[128 * 32];
  __shared__ unsigned short Bs0[128 * 32], Bs1[128 * 32];
  const int tid = threadIdx.x;
  const int t = xcd_chunk(blockIdx.x, 96);
  const int row0 = (t / 12) * 128, col0 = (t % 12) * 128;
  const int w = tid >> 6, lane = tid & 63;
  const int wy = w >> 1, wx = w & 1, l16 = lane & 15, quad = lane >> 4;
  floatx4 acc[4][4];
#pragma unroll
  for (int i = 0; i < 4; i++)
#pragma unroll
    for (int j = 0; j < 4; j++)
#pragma unroll
      for (int r = 0; r < 4; r++) acc[i][j][r] = 0.f;

  for (int k0 = 0; k0 < TD; k0 += 64) {
    stage_gll(Htb, TD, row0, k0, w, lane, As0);
    stage_gll(WqkT, TD, col0, k0, w, lane, Bs0);
    stage_gll(Htb, TD, row0, k0 + 32, w, lane, As1);
    stage_gll(WqkT, TD, col0, k0 + 32, w, lane, Bs1);
    __syncthreads();
    mfma_step_lin(As0, Bs0, wy, wx, l16, quad, acc);
    mfma_step_lin(As1, Bs1, wy, wx, l16, quad, acc);
    __syncthreads();
  }
#pragma unroll
  for (int i = 0; i < 4; i++)
#pragma unroll
    for (int j = 0; j < 4; j++) {
      const int col = col0 + wx * 64 + j * 16 + l16;
      const float bs = bias[col];
#pragma unroll
      for (int r = 0; r < 4; r++) {
        const int row = row0 + wy * 64 + i * 16 + quad * 4 + r;
        const float v = acc[i][j][r] + bs;
        if (col < TD) Q[(size_t)row * TD + col] = f2bf(v);
        else          Ko[(size_t)row * TD + (col - TD)] = f2bf(v);
      }
    }
}

// ==== K2: R9 two-pass no-max softmax + T5 s_setprio around compute clusters =
// Waves run barrier-free head loops at different phases -> T5's regime (m191).
#define OB_S 520
__global__ __launch_bounds__(256, 2)
void k2_attn(const unsigned short* __restrict__ Q, const unsigned short* __restrict__ Kb,
             const float* __restrict__ Ml, const float* __restrict__ am,
             unsigned short* __restrict__ Am) {
  __shared__ float4 ldsf4[1040];
  const int i0 = blockIdx.x;
  const int xcd = i0 & 7, jj = i0 >> 3;
  const int b = xcd + 8 * (jj & 1);
  const int q0 = (jj >> 1) * 16;
  const int tid = threadIdx.x;
  const int w = tid >> 6, lane = tid & 63;
  const int l16 = lane & 15, quad = lane >> 4;
  const int kbase = w * 128;

  const float* amb = am + b * TS;
  float amq[4], amk[8], maskv[8];
#pragma unroll
  for (int r = 0; r < 4; r++) amq[r] = amb[q0 + quad * 4 + r];
#pragma unroll
  for (int kt = 0; kt < 8; kt++) {
    amk[kt] = amb[kbase + kt * 16 + l16];
    maskv[kt] = (1.f - amk[kt]) * (-1e9f);
  }

  unsigned Mpk[TNCH][4][4];
#pragma unroll
  for (int i = 0; i < TNCH; i++)
#pragma unroll
    for (int r = 0; r < 4; r++) {
      const float* Mrow = Ml + ((size_t)((b * TNCH + i) * TS + q0 + quad * 4 + r)) * TS;
#pragma unroll
      for (int kt2 = 0; kt2 < 4; kt2++) {
        const int ke = kbase + kt2 * 32 + l16;
        const float me = Mrow[ke] * amk[kt2 * 2] * amq[r];
        const float mo = Mrow[ke + 16] * amk[kt2 * 2 + 1] * amq[r];
        Mpk[i][r][kt2] = f2bf2(me, mo);
      }
    }

  const unsigned short* qbase = Q + ((size_t)(b * TS + q0 + l16)) * TD + quad * 8;
  const unsigned short* kb0   = Kb + ((size_t)(b * TS + kbase + l16)) * TD + quad * 8;

  // ---------------- pass 1: denominators only (barrier-free loop) ----------
  for (int h = 0; h < TH; h++) {
    floatx4 sacc[8];
#pragma unroll
    for (int kt = 0; kt < 8; kt++)
#pragma unroll
      for (int r = 0; r < 4; r++) sacc[kt][r] = 0.f;
    __builtin_amdgcn_s_setprio(1);
#pragma unroll
    for (int dk = 0; dk < 2; dk++) {
      U4 a; a.u = *(const uint4*)(qbase + h * TDH + dk * 32);
#pragma unroll
      for (int kt = 0; kt < 8; kt++) {
        U4 bb; bb.u = *(const uint4*)(kb0 + (size_t)kt * 16 * TD + h * TDH + dk * 32);
        sacc[kt] = __builtin_amdgcn_mfma_f32_16x16x32_bf16(a.s, bb.s, sacc[kt], 0, 0, 0);
      }
    }
    __builtin_amdgcn_s_setprio(0);
    float e[8][4];
    float Zp[4] = {0.f, 0.f, 0.f, 0.f};
#pragma unroll
    for (int kt = 0; kt < 8; kt++)
#pragma unroll
      for (int r = 0; r < 4; r++) {
        const float v = __expf(sacc[kt][r] * SCALE + maskv[kt]);
        e[kt][r] = v;
        Zp[r] += v;
      }
    float dmp[TNCH][4];
#pragma unroll
    for (int i = 0; i < TNCH; i++)
#pragma unroll
      for (int r = 0; r < 4; r++) {
        float d = 0.f;
#pragma unroll
        for (int kt2 = 0; kt2 < 4; kt2++) {
          const unsigned u = Mpk[i][r][kt2];
          d += __uint_as_float(u << 16) * e[kt2 * 2][r];
          d += __uint_as_float(u & 0xffff0000u) * e[kt2 * 2 + 1][r];
        }
        dmp[i][r] = d;
      }
#pragma unroll
    for (int r = 0; r < 4; r++) {
#pragma unroll
      for (int off = 1; off < 16; off <<= 1) {
        Zp[r] += __shfl_xor(Zp[r], off);
        dmp[0][r] += __shfl_xor(dmp[0][r], off);
        dmp[1][r] += __shfl_xor(dmp[1][r], off);
        dmp[2][r] += __shfl_xor(dmp[2][r], off);
      }
    }
    if (l16 == 0) {
#pragma unroll
      for (int r = 0; r < 4; r++)
        ldsf4[(h * 16 + quad * 4 + r) * 4 + w] =
            make_float4(Zp[r], dmp[0][r], dmp[1][r], dmp[2][r]);
    }
  }
  __syncthreads();

  // ---------------- reduce partials -> per-(h,q) channel weights -----------
  if (tid < TH * 16) {
    const int h = tid >> 4, q = tid & 15;
    const int base = (h * 16 + q) * 4;
    const float4 p0 = ldsf4[base + 0];
    const float4 p1 = ldsf4[base + 1];
    const float4 p2 = ldsf4[base + 2];
    const float4 p3 = ldsf4[base + 3];
    const float Z  = p0.x + p1.x + p2.x + p3.x;
    const float d0 = p0.y + p1.y + p2.y + p3.y;
    const float d1 = p0.z + p1.z + p2.z + p3.z;
    const float d2 = p0.w + p1.w + p2.w + p3.w;
    const float ez = 1e-10f * Z + 1e-30f;
    ldsf4[768 + h * 16 + q] =
        make_float4(1.f / (d0 + ez), 1.f / (d1 + ez), 1.f / (d2 + ez), 0.f);
  }
  __syncthreads();

  // ---------------- pass 2: recompute e, accumulate (barrier-free loop) ----
  float acc[TNCH][8][4];
#pragma unroll
  for (int i = 0; i < TNCH; i++)
#pragma unroll
    for (int kt = 0; kt < 8; kt++)
#pragma unroll
      for (int r = 0; r < 4; r++) acc[i][kt][r] = 0.f;

  for (int h = 0; h < TH; h++) {
    floatx4 sacc[8];
#pragma unroll
    for (int kt = 0; kt < 8; kt++)
#pragma unroll
      for (int r = 0; r < 4; r++) sacc[kt][r] = 0.f;
    __builtin_amdgcn_s_setprio(1);
#pragma unroll
    for (int dk = 0; dk < 2; dk++) {
      U4 a; a.u = *(const uint4*)(qbase + h * TDH + dk * 32);
#pragma unroll
      for (int kt = 0; kt < 8; kt++) {
        U4 bb; bb.u = *(const uint4*)(kb0 + (size_t)kt * 16 * TD + h * TDH + dk * 32);
        sacc[kt] = __builtin_amdgcn_mfma_f32_16x16x32_bf16(a.s, bb.s, sacc[kt], 0, 0, 0);
      }
    }
    __builtin_amdgcn_s_setprio(0);
    float4 wv[4];
#pragma unroll
    for (int r = 0; r < 4; r++) wv[r] = ldsf4[768 + h * 16 + quad * 4 + r];
#pragma unroll
    for (int kt = 0; kt < 8; kt++)
#pragma unroll
      for (int r = 0; r < 4; r++) {
        const float v = __expf(sacc[kt][r] * SCALE + maskv[kt]);
        acc[0][kt][r] += v * wv[r].x;
        acc[1][kt][r] += v * wv[r].y;
        acc[2][kt][r] += v * wv[r].z;
      }
  }
  __syncthreads();

  unsigned short* obuf = (unsigned short*)ldsf4;
  const float inv_h = 1.f / (float)TH;
  for (int i = 0; i < TNCH; i++) {
#pragma unroll
    for (int r = 0; r < 4; r++) {
      const int q = q0 + quad * 4 + r;
      const float* Mrow = Ml + ((size_t)((b * TNCH + i) * TS + q)) * TS;
#pragma unroll
      for (int kt = 0; kt < 8; kt++) {
        const int k = kbase + kt * 16 + l16;
        const float mv = Mrow[k] * amk[kt] * amq[r];
        obuf[(quad * 4 + r) * OB_S + k] = f2bf(mv * acc[i][kt][r] * inv_h);
      }
    }
    __syncthreads();
#pragma unroll
    for (int it = 0; it < 4; it++) {
      const int idx = tid + it * 256;
      const int row = idx >> 6, c16 = idx & 63;
      const uint4 v = *(const uint4*)&obuf[row * OB_S + c16 * 8];
      *(uint4*)&Am[((size_t)((i * TB + b) * TS + q0 + row)) * TS + c16 * 8] = v;
    }
    __syncthreads();
  }
}

// ===== K3n: HtW_ch = Htb @ WgT_ch^T, stored TRANSPOSED per (ch,b): [768][512]
__global__ __launch_bounds__(256, 2)
void k3_htw(const unsigned short* __restrict__ Htb, const unsigned short* __restrict__ WgT,
            unsigned short* __restrict__ h0, unsigned short* __restrict__ h1,
            unsigned short* __restrict__ h2) {
  __shared__ unsigned short shmem[17536];   // union: 4x[128][32] staging | [128][137]
  unsigned short* As0 = shmem;
  unsigned short* Bs0 = shmem + 4096;
  unsigned short* As1 = shmem + 8192;
  unsigned short* Bs1 = shmem + 12288;
  const int tid = threadIdx.x;
  const int t = xcd_chunk(blockIdx.x, 144);       // 1152 blocks
  const int ch = t / 384;
  const int rc = t % 384;
  const int row0 = (rc / 6) * 128, col0 = (rc % 6) * 128;
  const unsigned short* Bt = WgT + (size_t)ch * TD * TD;
  unsigned short* H = (ch == 0) ? h0 : (ch == 1) ? h1 : h2;
  const int w = tid >> 6, lane = tid & 63;
  const int wy = w >> 1, wx = w & 1, l16 = lane & 15, quad = lane >> 4;
  floatx4 acc[4][4];
#pragma unroll
  for (int i = 0; i < 4; i++)
#pragma unroll
    for (int j = 0; j < 4; j++)
#pragma unroll
      for (int r = 0; r < 4; r++) acc[i][j][r] = 0.f;

  for (int k0 = 0; k0 < TD; k0 += 64) {
    stage_gll(Htb, TD, row0, k0, w, lane, As0);
    stage_gll(Bt, TD, col0, k0, w, lane, Bs0);
    stage_gll(Htb, TD, row0, k0 + 32, w, lane, As1);
    stage_gll(Bt, TD, col0, k0 + 32, w, lane, Bs1);
    __syncthreads();
    mfma_step_lin(As0, Bs0, wy, wx, l16, quad, acc);
    mfma_step_lin(As1, Bs1, wy, wx, l16, quad, acc);
    __syncthreads();
  }
  unsigned short* lds_t = shmem;
#pragma unroll
  for (int i = 0; i < 4; i++)
#pragma unroll
    for (int j = 0; j < 4; j++)
#pragma unroll
      for (int r = 0; r < 4; r++)
        lds_t[(wy * 64 + i * 16 + quad * 4 + r) * 137 + wx * 64 + j * 16 + l16] =
            f2bf(acc[i][j][r]);
  __syncthreads();
  const int b = row0 >> 9, s0 = row0 & 511;
#pragma unroll
  for (int it = 0; it < 8; it++) {
    const int idx = tid + it * 256;
    const int d_i = idx >> 4, chunk = idx & 15;
    unsigned v[4];
#pragma unroll
    for (int e = 0; e < 4; e++) {
      const unsigned short lo = lds_t[(chunk * 8 + 2 * e) * 137 + d_i];
      const unsigned short hi = lds_t[(chunk * 8 + 2 * e + 1) * 137 + d_i];
      v[e] = (unsigned)lo | ((unsigned)hi << 16);
    }
    *(uint4*)&H[((size_t)(b * TD + col0 + d_i)) * TS + s0 + chunk * 8] =
        make_uint4(v[0], v[1], v[2], v[3]);
  }
}

// == K4n: out = mean_ch relu(Am_ch[b] @ HtW_ch^T[b] + bg_ch) * am ============
__global__ __launch_bounds__(256, 2)
void k4_outn(const unsigned short* __restrict__ Am,
             const unsigned short* __restrict__ h0, const unsigned short* __restrict__ h1,
             const unsigned short* __restrict__ h2,
             const float* __restrict__ bg, const float* __restrict__ am,
             float* __restrict__ out) {
  __shared__ unsigned short As0[128 * 32], As1[128 * 32];
  __shared__ unsigned short Bs0[96 * 32], Bs1[96 * 32];
  const int tid = threadIdx.x;
  const int t = xcd_chunk(blockIdx.x, 64);        // 512 blocks
  const int row0 = (t >> 3) * 128, col0 = (t & 7) * 96;
  const int b = row0 >> 9, q0_ = row0 & 511;
  const int w = tid >> 6, lane = tid & 63;
  const int wy = w >> 1, wx = w & 1, l16 = lane & 15, quad = lane >> 4;
  float osum[4][3][4];
#pragma unroll
  for (int i = 0; i < 4; i++)
#pragma unroll
    for (int j = 0; j < 3; j++)
#pragma unroll
      for (int r = 0; r < 4; r++) osum[i][j][r] = 0.f;

  for (int ch = 0; ch < TNCH; ch++) {
    const unsigned short* A  = Am + (size_t)(ch * TB + b) * TS * TS;
    const unsigned short* Bt = ((ch == 0) ? h0 : (ch == 1) ? h1 : h2) + (size_t)b * TD * TS;
    floatx4 acc[4][3];
#pragma unroll
    for (int i = 0; i < 4; i++)
#pragma unroll
      for (int j = 0; j < 3; j++)
#pragma unroll
        for (int r = 0; r < 4; r++) acc[i][j][r] = 0.f;

    for (int k0 = 0; k0 < TS; k0 += 64) {
      stage_gll(A, TS, q0_, k0, w, lane, As0);
      stage_gll96(Bt, TS, col0, k0, w, lane, Bs0);
      stage_gll(A, TS, q0_, k0 + 32, w, lane, As1);
      stage_gll96(Bt, TS, col0, k0 + 32, w, lane, Bs1);
      __syncthreads();
      {
        short8 af[4], bfr[3];
#pragma unroll
        for (int i = 0; i < 4; i++) {
          U4 tt; tt.u = *(const uint4*)&As0[(wy * 64 + i * 16 + l16) * 32 + quad * 8];
          af[i] = tt.s;
        }
#pragma unroll
        for (int j = 0; j < 3; j++) {
          U4 tt; tt.u = *(const uint4*)&Bs0[(wx * 48 + j * 16 + l16) * 32 + quad * 8];
          bfr[j] = tt.s;
        }
#pragma unroll
        for (int i = 0; i < 4; i++)
#pragma unroll
          for (int j = 0; j < 3; j++)
            acc[i][j] = __builtin_amdgcn_mfma_f32_16x16x32_bf16(af[i], bfr[j], acc[i][j], 0, 0, 0);
      }
      {
        short8 af[4], bfr[3];
#pragma unroll
        for (int i = 0; i < 4; i++) {
          U4 tt; tt.u = *(const uint4*)&As1[(wy * 64 + i * 16 + l16) * 32 + quad * 8];
          af[i] = tt.s;
        }
#pragma unroll
        for (int j = 0; j < 3; j++) {
          U4 tt; tt.u = *(const uint4*)&Bs1[(wx * 48 + j * 16 + l16) * 32 + quad * 8];
          bfr[j] = tt.s;
        }
#pragma unroll
        for (int i = 0; i < 4; i++)
#pragma unroll
          for (int j = 0; j < 3; j++)
            acc[i][j] = __builtin_amdgcn_mfma_f32_16x16x32_bf16(af[i], bfr[j], acc[i][j], 0, 0, 0);
      }
      __syncthreads();
    }
#pragma unroll
    for (int i = 0; i < 4; i++)
#pragma unroll
      for (int j = 0; j < 3; j++) {
        const int col = col0 + wx * 48 + j * 16 + l16;
        const float bs = bg[ch * TD + col];
#pragma unroll
        for (int r = 0; r < 4; r++)
          osum[i][j][r] += fmaxf(acc[i][j][r] + bs, 0.f);
      }
  }
#pragma unroll
  for (int i = 0; i < 4; i++)
#pragma unroll
    for (int r = 0; r < 4; r++) {
      const int row = row0 + wy * 64 + i * 16 + quad * 4 + r;
      const float amr = am[row] * (1.f / 3.f);
#pragma unroll
      for (int j = 0; j < 3; j++) {
        const int col = col0 + wx * 48 + j * 16 + l16;
        out[(size_t)row * TD + col] = osum[i][j][r] * amr;
      }
    }
}

extern "C" void kernel_launch(void* const* d_in, const int* in_sizes, int n_in,
                              void* d_out, int out_size, void* d_ws, size_t ws_size,
                              hipStream_t stream) {
  const float* Ht    = (const float*)d_in[0];
  const float* Ml    = (const float*)d_in[1];
  const float* am    = (const float*)d_in[2];
  const float* W_qk  = (const float*)d_in[3];
  const float* b_qk  = (const float*)d_in[4];
  const float* W_gat = (const float*)d_in[5];
  const float* b_gat = (const float*)d_in[6];
  float* out = (float*)d_out;

  // ws layout (ushorts):
  //   Q / HtW0  [0,        SEG)      k1 writes Q; k3n overwrites as HtW0^T
  //   Kw / HtW1 [SEG,     2SEG)      k1 writes K; k3n overwrites as HtW1^T
  //   Htb       [2SEG,    3SEG)      bf16(Ht) — read by k1, k3n
  //   HtW2      [3SEG,    4SEG)
  //   WqkT      [4SEG, ...)          [1536][768]
  //   WgT       after WqkT           [3][768][768]
  //   Am        after WgT            [3][16][512][512]
  unsigned short* base = (unsigned short*)d_ws;
  const size_t SEG = (size_t)TB * TS * TD;            // 6291456
  unsigned short* Q    = base;
  unsigned short* Kw   = base + SEG;
  unsigned short* Htb  = base + 2 * SEG;
  unsigned short* HtW2 = base + 3 * SEG;
  unsigned short* WqkT = base + 4 * SEG;
  unsigned short* WgT  = WqkT + (size_t)TD * 2 * TD;
  unsigned short* Am   = WgT + (size_t)TNCH * TD * TD;
  unsigned short* HtW0 = Q;      // dead after k2
  unsigned short* HtW1 = Kw;     // dead after k2

  prep_all<<<dim3(5952), 256, 0, stream>>>(Ht, W_qk, W_gat, Htb, WqkT, WgT);

  k1_qk  <<<dim3(768),  256, 0, stream>>>(Htb, WqkT, b_qk, Q, Kw);
  k2_attn<<<dim3(512),  256, 0, stream>>>(Q, Kw, Ml, am, Am);
  k3_htw <<<dim3(1152), 256, 0, stream>>>(Htb, WgT, HtW0, HtW1, HtW2);
  k4_outn<<<dim3(512),  256, 0, stream>>>(Am, HtW0, HtW1, HtW2, b_gat, am, out);
}